// Round 9
// baseline (1024.240 us; speedup 1.0000x reference)
//
#include <hip/hip_runtime.h>
#include <stdint.h>

// ---------------- problem constants ----------------
constexpr int CB = 8, CC = 4, CN = 2048, CE = 512, CF = 2048;
constexpr long long TOT = (long long)CB * CC * CN * CE;
constexpr int GRP = 16;       // attention batches per LLC-resident group
constexpr int MCH = 65536;    // FFN rows (single chunk)
constexpr float SCALE = 0.04419417382415922f;  // 1/sqrt(512)
constexpr float MASK_SCALE = 5.0f;
constexpr float EPS = 1e-5f;

typedef unsigned short bf16_t;
typedef __attribute__((ext_vector_type(4))) float f32x4;
typedef __attribute__((ext_vector_type(8))) short s16x8;

#define DEV static __device__ __forceinline__

DEV unsigned short f2bf(float f) {
    unsigned u = __float_as_uint(f);
    unsigned r = (u + 0x7fffu + ((u >> 16) & 1u)) >> 16;
    return (unsigned short)r;
}
DEV float bf2f(unsigned short b) {
    return __uint_as_float(((unsigned)b) << 16);
}

typedef const __attribute__((address_space(1))) unsigned int* gptr_t;
typedef __attribute__((address_space(3))) unsigned int* lptr_t;
DEV void async16(const void* g, void* l) {
    __builtin_amdgcn_global_load_lds((gptr_t)g, (lptr_t)l, 16, 0, 0);
}

#define FULL_BAR() do { asm volatile("" ::: "memory"); __builtin_amdgcn_s_barrier(); asm volatile("" ::: "memory"); } while (0)
#define LGKM0() asm volatile("s_waitcnt lgkmcnt(0)" ::: "memory")
#define SCHED0() __builtin_amdgcn_sched_barrier(0)
#define VMCNT(N_) asm volatile("s_waitcnt vmcnt(" #N_ ")" ::: "memory")

// ---------------- reductions (256-thread blocks = 4 waves) ----------------
DEV float blockSum256(float v, float* sm) {
    #pragma unroll
    for (int o = 32; o; o >>= 1) v += __shfl_xor(v, o);
    int w = threadIdx.x >> 6;
    __syncthreads();
    if ((threadIdx.x & 63) == 0) sm[w] = v;
    __syncthreads();
    return sm[0] + sm[1] + sm[2] + sm[3];
}
DEV float blockMax256(float v, float* sm) {
    #pragma unroll
    for (int o = 32; o; o >>= 1) v = fmaxf(v, __shfl_xor(v, o));
    int w = threadIdx.x >> 6;
    __syncthreads();
    if ((threadIdx.x & 63) == 0) sm[w] = v;
    __syncthreads();
    return fmaxf(fmaxf(sm[0], sm[1]), fmaxf(sm[2], sm[3]));
}

// ---------------- fused fp32->bf16 convert + batched transpose ----------------
__global__ __launch_bounds__(256) void cvt_transpose(
    const float* __restrict__ in, bf16_t* __restrict__ outN,
    bf16_t* __restrict__ outT) {
    __shared__ bf16_t tile[32][33];
    const float* inz = in + (size_t)blockIdx.z * CN * CE;
    bf16_t* oN = outN + (size_t)blockIdx.z * CN * CE;
    bf16_t* oT = outT + (size_t)blockIdx.z * CE * CN;
    int rb = blockIdx.y * 32;   // n rows
    int cb = blockIdx.x * 32;   // e cols
    int tx = threadIdx.x & 31, ty = threadIdx.x >> 5;
    #pragma unroll
    for (int i = 0; i < 32; i += 8) {
        float v = inz[(size_t)(rb + ty + i) * CE + cb + tx];
        unsigned short h = f2bf(v);
        oN[(size_t)(rb + ty + i) * CE + cb + tx] = h;
        tile[ty + i][tx] = h;
    }
    __syncthreads();
    #pragma unroll
    for (int i = 0; i < 32; i += 8)
        oT[(size_t)(cb + ty + i) * CN + rb + tx] = tile[tx][ty + i];
}

// ---------------- transpose fp32[R][C] -> bf16[C][R] (weights) ----------------
__global__ __launch_bounds__(256) void transpose_f32_bf16(
    const float* __restrict__ in, bf16_t* __restrict__ out,
    int R, int Cc) {
    __shared__ float tile[32][33];
    int rb = blockIdx.y * 32, cb = blockIdx.x * 32;
    int tx = threadIdx.x & 31, ty = threadIdx.x >> 5;
    #pragma unroll
    for (int i = 0; i < 32; i += 8)
        tile[ty + i][tx] = in[(size_t)(rb + ty + i) * Cc + cb + tx];
    __syncthreads();
    #pragma unroll
    for (int i = 0; i < 32; i += 8)
        out[(size_t)(cb + ty + i) * R + rb + tx] = f2bf(tile[tx][ty + i]);
}

// ============ 128x128 GEMM, 4 blocks/CU, async dbuf, 1 barrier/K-tile ========
// C[M,Nc] = A[M,K] @ B[Nc,K]^T, bf16 in, fp32 acc. 4 waves (2x2), BK=32,
// double-buffered 32 KiB static LDS. Merged schedule per K-tile:
//   {ds_read 8 (buf p) ; push 4 async16 (tile i+1 -> buf p^1) ; lgkm0 ;
//    16 MFMA ; vmcnt(0) ; barrier}
// Race ledger: reads of p complete before own lgkm0 < bar(i); p overwritten
// only by push(i+2) issued after bar(i+1) -> one barrier suffices. Reads of
// p^1 at iter i+1 are safe: all waves drained their pushes (vmcnt(0)) before
// bar(i). LDS swizzle: 16B slot q^((rr0>>1)&3), pre-swizzled global source;
// bank map = 8 distinct quads per 16-lane group, 2-way only (free).
// EPI 1: +bias relu bf16. 3: alpha*bf16. 4: +bias bf16.
template <int EPI>
__global__ __launch_bounds__(256, 4) void gemm128(
    const bf16_t* __restrict__ A, const bf16_t* __restrict__ B,
    void* __restrict__ Cptr, const float* __restrict__ bias, float alpha,
    int Nc, int K, long long sA, long long sB, long long sC) {
    __shared__ bf16_t As[2][128 * 32];
    __shared__ bf16_t Bs[2][128 * 32];

    // ---- XCD-aware bijective swizzle (requires nwg % 8 == 0) ----
    int bx, by, bz;
    {
        int gx = gridDim.x, gy = gridDim.y;
        int nwg = gx * gy * gridDim.z;
        int flat = blockIdx.x + gx * (blockIdx.y + gy * blockIdx.z);
        int wg = (nwg & 7) ? flat : ((flat & 7) * (nwg >> 3) + (flat >> 3));
        bx = wg % gx;
        int tmp = wg / gx;
        by = tmp % gy;
        bz = tmp / gy;
    }

    const int t = threadIdx.x;
    const int lane = t & 63, wid = t >> 6;
    const int wr = wid >> 1, wc = wid & 1;
    const int brow = by * 128, bcol = bx * 128;
    const int NT = K >> 5;

    // staging: thread t -> dest elem t*8 in a 64-row half (row t>>2, slot t&3);
    // source column pre-swizzled so LDS[row][slot] holds k-chunk slot^((row>>1)&3)
    const int r0 = t >> 2;
    const int srcOff = (((t & 3) ^ ((t >> 3) & 3)) * 8);
    const bf16_t* aP = A + (size_t)bz * sA + (size_t)(brow + r0) * K + srcOff;
    const bf16_t* bP = B + (size_t)bz * sB + (size_t)(bcol + r0) * K + srcOff;
    const size_t rK64 = (size_t)64 * K;

    #define PUSH(i_, p_) do { \
        const bf16_t* sa_ = aP + (size_t)(i_) * 32; \
        const bf16_t* sb_ = bP + (size_t)(i_) * 32; \
        async16(sa_, &As[p_][t * 8]); \
        async16(sa_ + rK64, &As[p_][2048 + t * 8]); \
        async16(sb_, &Bs[p_][t * 8]); \
        async16(sb_ + rK64, &Bs[p_][2048 + t * 8]); \
    } while (0)

    const int q = lane >> 4, rr0 = lane & 15;
    const int rslot = ((q ^ ((rr0 >> 1) & 3)) << 3);  // read-side swizzled slot
    f32x4 acc[4][4] = {};

    PUSH(0, 0);
    VMCNT(0);
    FULL_BAR();

    for (int i = 0; i < NT; ++i) {
        const int p = i & 1;
        s16x8 af[4], bv[4];
        #pragma unroll
        for (int m = 0; m < 4; ++m)
            af[m] = *(const s16x8*)&As[p][(wr * 64 + m * 16 + rr0) * 32 + rslot];
        #pragma unroll
        for (int n = 0; n < 4; ++n)
            bv[n] = *(const s16x8*)&Bs[p][(wc * 64 + n * 16 + rr0) * 32 + rslot];
        if (i + 1 < NT) PUSH(i + 1, p ^ 1);
        LGKM0(); SCHED0();
        __builtin_amdgcn_s_setprio(1);
        #pragma unroll
        for (int m = 0; m < 4; ++m)
            #pragma unroll
            for (int n = 0; n < 4; ++n)
                acc[m][n] = __builtin_amdgcn_mfma_f32_16x16x32_bf16(af[m], bv[n], acc[m][n], 0, 0, 0);
        __builtin_amdgcn_s_setprio(0);
        VMCNT(0);
        FULL_BAR();
    }

    // ---- epilogue: shfl col-pairing -> dword stores ----
    size_t cz = (size_t)bz * sC;
    bf16_t* Cb = (bf16_t*)Cptr + cz;
    const int lo = lane & 1;
    #pragma unroll
    for (int m = 0; m < 4; m++) {
        #pragma unroll
        for (int n = 0; n < 4; n++) {
            int col = bcol + wc * 64 + n * 16 + rr0;
            float bvv = (EPI == 1 || EPI == 4) ? bias[col] : 0.f;
            unsigned words[4];
            #pragma unroll
            for (int j = 0; j < 4; j++) {
                float v = acc[m][n][j] + bvv;
                if constexpr (EPI == 1) v = fmaxf(v, 0.f);
                if constexpr (EPI == 3) v *= alpha;
                unsigned h = f2bf(v);
                unsigned o = (unsigned)__shfl_xor((int)h, 1);
                words[j] = lo ? (o | (h << 16)) : (h | (o << 16));
            }
            int row = brow + wr * 64 + m * 16 + q * 4 + lo * 2;
            int cp = col & ~1;
            *(unsigned*)&Cb[(size_t)row * Nc + cp] = words[lo * 2];
            *(unsigned*)&Cb[(size_t)(row + 1) * Nc + cp] = words[lo * 2 + 1];
        }
    }
    #undef PUSH
}

// ---------------- softmax: bf16 scores (pre-scaled) in-place -> bf16 probs ---
__global__ __launch_bounds__(256) void softmax_bf16(
    bf16_t* __restrict__ S, const float* __restrict__ mask, int bc0) {
    __shared__ float sm[4];
    int gr = blockIdx.x;
    int b = (bc0 + (gr >> 11)) >> 2;
    bf16_t* row = S + (size_t)gr * CN;
    int tid = threadIdx.x;
    const float* mrow = mask + (size_t)b * CN + tid * 8;
    s16x8 v = *(const s16x8*)(row + tid * 8);
    float4 m0 = *(const float4*)(mrow);
    float4 m1 = *(const float4*)(mrow + 4);
    float x[8];
    x[0] = bf2f((unsigned short)v[0]) - m0.x * MASK_SCALE;
    x[1] = bf2f((unsigned short)v[1]) - m0.y * MASK_SCALE;
    x[2] = bf2f((unsigned short)v[2]) - m0.z * MASK_SCALE;
    x[3] = bf2f((unsigned short)v[3]) - m0.w * MASK_SCALE;
    x[4] = bf2f((unsigned short)v[4]) - m1.x * MASK_SCALE;
    x[5] = bf2f((unsigned short)v[5]) - m1.y * MASK_SCALE;
    x[6] = bf2f((unsigned short)v[6]) - m1.z * MASK_SCALE;
    x[7] = bf2f((unsigned short)v[7]) - m1.w * MASK_SCALE;
    float mx = -3.4e38f;
    #pragma unroll
    for (int i = 0; i < 8; i++) mx = fmaxf(mx, x[i]);
    mx = blockMax256(mx, sm);
    float s = 0.f;
    #pragma unroll
    for (int i = 0; i < 8; i++) { x[i] = __expf(x[i] - mx); s += x[i]; }
    s = blockSum256(s, sm);
    float inv = 1.f / s;
    s16x8 u;
    #pragma unroll
    for (int i = 0; i < 8; i++) u[i] = (short)f2bf(x[i] * inv);
    *(s16x8*)(row + tid * 8) = u;
}

// ---------------- residual + layernorm kernels (E=512, one block/row) --------
__global__ __launch_bounds__(256) void ln1_kernel(
    const bf16_t* __restrict__ src, const bf16_t* __restrict__ ao,
    const float* __restrict__ g, const float* __restrict__ be,
    bf16_t* __restrict__ o) {
    __shared__ float sm[4];
    size_t base = (size_t)blockIdx.x * CE;
    int e = threadIdx.x * 2;
    ushort2 s = *(const ushort2*)&src[base + e];
    ushort2 a = *(const ushort2*)&ao[base + e];
    float x0 = bf2f(s.x) + bf2f(a.x), x1 = bf2f(s.y) + bf2f(a.y);
    float mu = blockSum256(x0 + x1, sm) * (1.f / CE);
    float d0 = x0 - mu, d1 = x1 - mu;
    float var = blockSum256(d0 * d0 + d1 * d1, sm) * (1.f / CE);
    float rs = rsqrtf(var + EPS);
    ushort2 w;
    w.x = f2bf(d0 * rs * g[e] + be[e]);
    w.y = f2bf(d1 * rs * g[e + 1] + be[e + 1]);
    *(ushort2*)&o[base + e] = w;
}

__global__ __launch_bounds__(256) void ln2_kernel(
    const bf16_t* __restrict__ a, const bf16_t* __restrict__ b,
    const float* __restrict__ g, const float* __restrict__ be,
    float* __restrict__ o) {
    __shared__ float sm[4];
    size_t base = (size_t)blockIdx.x * CE;
    int e = threadIdx.x * 2;
    ushort2 aa = *(const ushort2*)&a[base + e];
    ushort2 bb = *(const ushort2*)&b[base + e];
    float x0 = bf2f(aa.x) + bf2f(bb.x), x1 = bf2f(aa.y) + bf2f(bb.y);
    float mu = blockSum256(x0 + x1, sm) * (1.f / CE);
    float d0 = x0 - mu, d1 = x1 - mu;
    float var = blockSum256(d0 * d0 + d1 * d1, sm) * (1.f / CE);
    float rs = rsqrtf(var + EPS);
    float2 w;
    w.x = d0 * rs * g[e] + be[e];
    w.y = d1 * rs * g[e + 1] + be[e + 1];
    *(float2*)&o[base + e] = w;
}

// ---------------- host ----------------
extern "C" void kernel_launch(void* const* d_in, const int* in_sizes, int n_in,
                              void* d_out, int out_size, void* d_ws, size_t ws_size,
                              hipStream_t stream) {
    const float* src  = (const float*)d_in[0];
    const float* mask = (const float*)d_in[1];
    const float* W1   = (const float*)d_in[2];
    const float* b1   = (const float*)d_in[3];
    const float* W2   = (const float*)d_in[4];
    const float* b2   = (const float*)d_in[5];
    const float* g1   = (const float*)d_in[6];
    const float* be1  = (const float*)d_in[7];
    const float* g2   = (const float*)d_in[8];
    const float* be2  = (const float*)d_in[9];
    float* out = (float*)d_out;
    char* ws = (char*)d_ws;

    // ---- workspace layout (MiB offsets) ----
    // [0,256)   scores/probs bf16 (all 32)  | FFN: [0,64)=src2, [64,128)=ff, [128,384)=H
    // [256,320) src_bf
    // [320,384) srcT
    // [384,448) attnO (bf16)
    // [448,452) W1T, W2T
    const size_t MB = 1024 * 1024;
    bf16_t* probs  = (bf16_t*)(ws);              // scores in-place -> probs
    bf16_t* src_bf = (bf16_t*)(ws + 256 * MB);
    bf16_t* srcT   = (bf16_t*)(ws + 320 * MB);
    bf16_t* attnO  = (bf16_t*)(ws + 384 * MB);
    bf16_t* W1T    = (bf16_t*)(ws + 448 * MB);
    bf16_t* W2T    = (bf16_t*)(ws + 450 * MB);
    bf16_t* src2   = (bf16_t*)(ws);              // overlays probs (dead after PV)
    bf16_t* ff     = (bf16_t*)(ws + 64 * MB);    // overlays probs
    bf16_t* H      = (bf16_t*)(ws + 128 * MB);   // overlays probs tail
    if (ws_size < 452 * MB) return;

    // ---- conversions (src conv + transpose fused; weights separate) ----
    cvt_transpose<<<dim3(CE / 32, CN / 32, 32), 256, 0, stream>>>(src, src_bf, srcT);
    transpose_f32_bf16<<<dim3(CF / 32, CE / 32, 1), 256, 0, stream>>>(W1, W1T, CE, CF);
    transpose_f32_bf16<<<dim3(CE / 32, CF / 32, 1), 256, 0, stream>>>(W2, W2T, CF, CE);

    // ---- attention in LLC-resident groups: scores -> softmax -> PV ----
    for (int g0 = 0; g0 < CB * CC; g0 += GRP) {
        const bf16_t* srcb = src_bf + (size_t)g0 * CN * CE;
        bf16_t* probs_g = probs + (size_t)g0 * CN * CN;
        gemm128<3><<<dim3(CN / 128, CN / 128, GRP), 256, 0, stream>>>(
            srcb, srcb, probs_g, nullptr, SCALE, CN, CE,
            (long long)CN * CE, (long long)CN * CE, (long long)CN * CN);
        softmax_bf16<<<dim3(GRP * CN), 256, 0, stream>>>(probs_g, mask, g0);
        gemm128<3><<<dim3(CE / 128, CN / 128, GRP), 256, 0, stream>>>(
            probs_g, srcT + (size_t)g0 * CE * CN, attnO + (size_t)g0 * CN * CE,
            nullptr, 1.0f, CE, CN,
            (long long)CN * CN, (long long)CE * CN, (long long)CN * CE);
    }
    ln1_kernel<<<dim3(CB * CC * CN), 256, 0, stream>>>(src_bf, attnO, g1, be1, src2);

    // ---- FFN + final LN (single chunk) ----
    gemm128<1><<<dim3(CF / 128, MCH / 128, 1), 256, 0, stream>>>(
        src2, W1T, H, b1, 1.0f, CF, CE, 0, 0, 0);
    gemm128<4><<<dim3(CE / 128, MCH / 128, 1), 256, 0, stream>>>(
        H, W2T, ff, b2, 1.0f, CE, CF, 0, 0, 0);
    ln2_kernel<<<dim3(MCH), 256, 0, stream>>>(src2, ff, g2, be2, out);
}

// Round 10
// 878.444 us; speedup vs baseline: 1.1660x; 1.1660x over previous
//
#include <hip/hip_runtime.h>
#include <stdint.h>

// ---------------- problem constants ----------------
constexpr int CB = 8, CC = 4, CN = 2048, CE = 512, CF = 2048;
constexpr long long TOT = (long long)CB * CC * CN * CE;
constexpr int GRP = 16;       // attention batches per LLC-resident group
constexpr int MCH = 65536;    // FFN rows (single chunk)
constexpr float SCALE = 0.04419417382415922f;  // 1/sqrt(512)
constexpr float MASK_SCALE = 5.0f;
constexpr float EPS = 1e-5f;

typedef unsigned short bf16_t;
typedef __attribute__((ext_vector_type(4))) float f32x4;
typedef __attribute__((ext_vector_type(8))) short s16x8;

#define DEV static __device__ __forceinline__

DEV unsigned short f2bf(float f) {
    unsigned u = __float_as_uint(f);
    unsigned r = (u + 0x7fffu + ((u >> 16) & 1u)) >> 16;
    return (unsigned short)r;
}
DEV float bf2f(unsigned short b) {
    return __uint_as_float(((unsigned)b) << 16);
}

typedef const __attribute__((address_space(1))) unsigned int* gptr_t;
typedef __attribute__((address_space(3))) unsigned int* lptr_t;
DEV void async16(const void* g, void* l) {
    __builtin_amdgcn_global_load_lds((gptr_t)g, (lptr_t)l, 16, 0, 0);
}

#define FULL_BAR() do { asm volatile("" ::: "memory"); __builtin_amdgcn_s_barrier(); asm volatile("" ::: "memory"); } while (0)
#define LGKM0() asm volatile("s_waitcnt lgkmcnt(0)" ::: "memory")
#define VMCNT(N_) asm volatile("s_waitcnt vmcnt(" #N_ ")" ::: "memory")

// ---------------- reductions (256-thread blocks = 4 waves) ----------------
DEV float blockSum256(float v, float* sm) {
    #pragma unroll
    for (int o = 32; o; o >>= 1) v += __shfl_xor(v, o);
    int w = threadIdx.x >> 6;
    __syncthreads();
    if ((threadIdx.x & 63) == 0) sm[w] = v;
    __syncthreads();
    return sm[0] + sm[1] + sm[2] + sm[3];
}
DEV float blockMax256(float v, float* sm) {
    #pragma unroll
    for (int o = 32; o; o >>= 1) v = fmaxf(v, __shfl_xor(v, o));
    int w = threadIdx.x >> 6;
    __syncthreads();
    if ((threadIdx.x & 63) == 0) sm[w] = v;
    __syncthreads();
    return fmaxf(fmaxf(sm[0], sm[1]), fmaxf(sm[2], sm[3]));
}

// ---------------- fused fp32->bf16 convert + batched transpose ----------------
__global__ __launch_bounds__(256) void cvt_transpose(
    const float* __restrict__ in, bf16_t* __restrict__ outN,
    bf16_t* __restrict__ outT) {
    __shared__ bf16_t tile[32][33];
    const float* inz = in + (size_t)blockIdx.z * CN * CE;
    bf16_t* oN = outN + (size_t)blockIdx.z * CN * CE;
    bf16_t* oT = outT + (size_t)blockIdx.z * CE * CN;
    int rb = blockIdx.y * 32;   // n rows
    int cb = blockIdx.x * 32;   // e cols
    int tx = threadIdx.x & 31, ty = threadIdx.x >> 5;
    #pragma unroll
    for (int i = 0; i < 32; i += 8) {
        float v = inz[(size_t)(rb + ty + i) * CE + cb + tx];
        unsigned short h = f2bf(v);
        oN[(size_t)(rb + ty + i) * CE + cb + tx] = h;
        tile[ty + i][tx] = h;
    }
    __syncthreads();
    #pragma unroll
    for (int i = 0; i < 32; i += 8)
        oT[(size_t)(cb + ty + i) * CN + rb + tx] = tile[tx][ty + i];
}

// ---------------- transpose fp32[R][C] -> bf16[C][R] (weights) ----------------
__global__ __launch_bounds__(256) void transpose_f32_bf16(
    const float* __restrict__ in, bf16_t* __restrict__ out,
    int R, int Cc) {
    __shared__ float tile[32][33];
    int rb = blockIdx.y * 32, cb = blockIdx.x * 32;
    int tx = threadIdx.x & 31, ty = threadIdx.x >> 5;
    #pragma unroll
    for (int i = 0; i < 32; i += 8)
        tile[ty + i][tx] = in[(size_t)(rb + ty + i) * Cc + cb + tx];
    __syncthreads();
    #pragma unroll
    for (int i = 0; i < 32; i += 8)
        out[(size_t)(cb + ty + i) * R + rb + tx] = f2bf(tile[tx][ty + i]);
}

// ======== shared pieces of the 256x256 GEMM (R1-proven schedule) ========
// bf16 in, fp32 acc, 8 waves (2Mx4N), BK=64, 128KiB dyn LDS double-buffered.
// XOR swizzle on 16B k-slots; pre-swizzled global source.
#define GEMM_CORE_DECLS() \
    extern __shared__ bf16_t lds[]; \
    bf16_t* AsL = lds; \
    bf16_t* BsL = lds + 32768; \
    const int t = threadIdx.x; \
    const int lane = t & 63, wid = t >> 6; \
    const int wr = wid >> 2, wc = wid & 3; \
    const int NT = K >> 6; \
    const int r0 = t >> 3, s0 = t & 7; \
    const int ce = ((s0 ^ (r0 & 7)) << 3); \
    const bf16_t* aP0 = Az + (size_t)(brow + r0) * K + ce; \
    const bf16_t* bP0 = Bz + (size_t)(bcol + r0) * K + ce; \
    const size_t rK64 = (size_t)64 * K; \
    const size_t h128K = rK64 * 2; \
    const int q = lane >> 4, rr0 = lane & 15, xmask = rr0 & 7; \
    s16x8 af[4][2]; \
    s16x8 bv[2][2][2]; \
    f32x4 acc[2][2][4][2] = {};

#define STAGE_A(kt_, h_) do { \
    bf16_t* d_ = AsL + ((((kt_) & 1) * 2 + (h_)) * 8192); \
    const bf16_t* s_ = aP0 + (size_t)(h_) * h128K + (size_t)(kt_) * 64; \
    async16(s_, d_ + t * 8); \
    async16(s_ + rK64, d_ + 4096 + t * 8); \
} while (0)
#define STAGE_B(kt_, h_) do { \
    bf16_t* d_ = BsL + ((((kt_) & 1) * 2 + (h_)) * 8192); \
    const bf16_t* s_ = bP0 + (size_t)(h_) * h128K + (size_t)(kt_) * 64; \
    async16(s_, d_ + t * 8); \
    async16(s_ + rK64, d_ + 4096 + t * 8); \
} while (0)
#define READ_A(ktp_, qm_) do { \
    const bf16_t* base_ = AsL + (((ktp_) * 2 + (qm_)) * 8192); \
    _Pragma("unroll") for (int m_ = 0; m_ < 4; ++m_) \
    _Pragma("unroll") for (int ks_ = 0; ks_ < 2; ++ks_) \
        af[m_][ks_] = *(const s16x8*)(base_ + (wr * 64 + m_ * 16 + rr0) * 64 + (((ks_ * 4 + q) ^ xmask) << 3)); \
} while (0)
#define READ_B(ktp_, qn_) do { \
    const bf16_t* base_ = BsL + (((ktp_) * 2 + (qn_)) * 8192); \
    _Pragma("unroll") for (int n_ = 0; n_ < 2; ++n_) \
    _Pragma("unroll") for (int ks_ = 0; ks_ < 2; ++ks_) \
        bv[qn_][n_][ks_] = *(const s16x8*)(base_ + (wc * 32 + n_ * 16 + rr0) * 64 + (((ks_ * 4 + q) ^ xmask) << 3)); \
} while (0)
#define MFMA_Q(qm_, qn_) do { \
    __builtin_amdgcn_s_setprio(1); \
    _Pragma("unroll") for (int m_ = 0; m_ < 4; ++m_) \
    _Pragma("unroll") for (int n_ = 0; n_ < 2; ++n_) \
    _Pragma("unroll") for (int ks_ = 0; ks_ < 2; ++ks_) \
        acc[qm_][qn_][m_][n_] = __builtin_amdgcn_mfma_f32_16x16x32_bf16( \
            af[m_][ks_], bv[qn_][n_][ks_], acc[qm_][qn_][m_][n_], 0, 0, 0); \
    __builtin_amdgcn_s_setprio(0); \
} while (0)

// R1-exact main loop (measured 875 TF on PV, 781 TF on scores, in rounds 2-4)
#define GEMM_MAIN_LOOP() \
    STAGE_A(0, 0); STAGE_B(0, 0); STAGE_B(0, 1); STAGE_A(0, 1); \
    if (1 < NT) { \
        STAGE_A(1, 0); STAGE_B(1, 0); \
        VMCNT(4); \
    } else { \
        VMCNT(0); \
    } \
    FULL_BAR(); \
    for (int kt = 0; kt < NT; ++kt) { \
        const int ktp = kt & 1; \
        READ_A(ktp, 0); \
        READ_B(ktp, 0); \
        if (kt + 1 < NT) STAGE_B(kt + 1, 1); \
        FULL_BAR(); \
        LGKM0(); \
        MFMA_Q(0, 0); \
        FULL_BAR(); \
        READ_B(ktp, 1); \
        if (kt + 1 < NT) STAGE_A(kt + 1, 1); \
        FULL_BAR(); \
        LGKM0(); \
        MFMA_Q(0, 1); \
        FULL_BAR(); \
        READ_A(ktp, 1); \
        if (kt + 2 < NT) STAGE_A(kt + 2, 0); \
        FULL_BAR(); \
        LGKM0(); \
        MFMA_Q(1, 0); \
        FULL_BAR(); \
        if (kt + 2 < NT) { \
            STAGE_B(kt + 2, 0); \
            VMCNT(4); \
        } else { \
            VMCNT(0); \
        } \
        FULL_BAR(); \
        MFMA_Q(1, 1); \
        FULL_BAR(); \
    }

// ============ general 256x256 GEMM: C[M,Nc] = A[M,K] @ B[Nc,K]^T ============
// EPI 1: +bias relu bf16. 3: alpha*bf16. 4: +bias bf16.
template <int EPI>
__global__ __launch_bounds__(512, 2) void gemm256(
    const bf16_t* __restrict__ A, const bf16_t* __restrict__ B,
    void* __restrict__ Cptr, const float* __restrict__ bias, float alpha,
    int Nc, int K, long long sA, long long sB, long long sC) {
    // ---- XCD-aware bijective swizzle (requires nwg % 8 == 0) ----
    int bx, by, bz;
    {
        int gx = gridDim.x, gy = gridDim.y;
        int nwg = gx * gy * gridDim.z;
        int flat = blockIdx.x + gx * (blockIdx.y + gy * blockIdx.z);
        int wg = (nwg & 7) ? flat : ((flat & 7) * (nwg >> 3) + (flat >> 3));
        bx = wg % gx;
        int tmp = wg / gx;
        by = tmp % gy;
        bz = tmp / gy;
    }
    const bf16_t* Az = A + (size_t)bz * sA;
    const bf16_t* Bz = B + (size_t)bz * sB;
    const int brow = by * 256, bcol = bx * 256;

    GEMM_CORE_DECLS();
    GEMM_MAIN_LOOP();

    // ---- epilogue: shfl col-pairing -> dword stores ----
    size_t cz = (size_t)bz * sC;
    bf16_t* Cb = (bf16_t*)Cptr + cz;
    const int lo = lane & 1;
    #pragma unroll
    for (int qm = 0; qm < 2; ++qm)
    #pragma unroll
    for (int qn = 0; qn < 2; ++qn)
    #pragma unroll
    for (int n = 0; n < 2; ++n) {
        int col = bcol + qn * 128 + wc * 32 + n * 16 + rr0;
        float bvv = (EPI == 1 || EPI == 4) ? bias[col] : 0.f;
        #pragma unroll
        for (int m = 0; m < 4; ++m) {
            unsigned words[4];
            #pragma unroll
            for (int j = 0; j < 4; ++j) {
                float v = acc[qm][qn][m][n][j] + bvv;
                if constexpr (EPI == 1) v = fmaxf(v, 0.f);
                if constexpr (EPI == 3) v *= alpha;
                unsigned h = f2bf(v);
                unsigned o = (unsigned)__shfl_xor((int)h, 1);
                words[j] = lo ? (o | (h << 16)) : (h | (o << 16));
            }
            int row = brow + qm * 128 + wr * 64 + m * 16 + q * 4 + lo * 2;
            int cp = col & ~1;
            *(unsigned*)&Cb[(size_t)row * Nc + cp] = words[lo * 2];
            *(unsigned*)&Cb[(size_t)(row + 1) * Nc + cp] = words[lo * 2 + 1];
        }
    }
}

// ============ symmetric scores GEMM: S = alpha * X @ X^T (lower-tri tiles) ===
// grid (36, 1, z): blockIdx.x enumerates lower-triangle tiles (i>=j) of the
// 8x8 tile grid; off-diagonal tiles also write the mirrored tile S[j,i] via
// aligned 8B ushort4 stores (the 4 acc j's are consecutive mirror columns).
__global__ __launch_bounds__(512, 2) void gemm256_sym(
    const bf16_t* __restrict__ A, bf16_t* __restrict__ Cptr, float alpha,
    int Nc, int K, long long sA, long long sC) {
    int bx, by, bz;
    {
        int gx = gridDim.x;                      // 36
        int nwg = gx * gridDim.z;
        int flat = blockIdx.x + gx * blockIdx.z;
        int wg = (nwg & 7) ? flat : ((flat & 7) * (nwg >> 3) + (flat >> 3));
        int tri = wg % gx;
        bz = wg / gx;
        int i = 0, b = 0;
        while (b + i + 1 <= tri) { b += i + 1; i++; }
        by = i;          // row tile
        bx = tri - b;    // col tile, bx <= by
    }
    const bf16_t* Az = A + (size_t)bz * sA;
    const bf16_t* Bz = Az;
    const int brow = by * 256, bcol = bx * 256;

    GEMM_CORE_DECLS();
    GEMM_MAIN_LOOP();

    size_t cz = (size_t)bz * sC;
    bf16_t* Cb = (bf16_t*)Cptr + cz;
    const int lo = lane & 1;
    const bool mirror = (bx != by);
    #pragma unroll
    for (int qm = 0; qm < 2; ++qm)
    #pragma unroll
    for (int qn = 0; qn < 2; ++qn)
    #pragma unroll
    for (int n = 0; n < 2; ++n) {
        int col = bcol + qn * 128 + wc * 32 + n * 16 + rr0;
        #pragma unroll
        for (int m = 0; m < 4; ++m) {
            unsigned short hh[4];
            #pragma unroll
            for (int j = 0; j < 4; ++j)
                hh[j] = f2bf(acc[qm][qn][m][n][j] * alpha);
            // normal paired store into S[row, col]
            unsigned words[4];
            #pragma unroll
            for (int j = 0; j < 4; ++j) {
                unsigned h = hh[j];
                unsigned o = (unsigned)__shfl_xor((int)h, 1);
                words[j] = lo ? (o | (h << 16)) : (h | (o << 16));
            }
            int row = brow + qm * 128 + wr * 64 + m * 16 + q * 4 + lo * 2;
            int cp = col & ~1;
            *(unsigned*)&Cb[(size_t)row * Nc + cp] = words[lo * 2];
            *(unsigned*)&Cb[(size_t)(row + 1) * Nc + cp] = words[lo * 2 + 1];
            // mirror store into S[col, row0..row0+3]
            if (mirror) {
                int mcol0 = brow + qm * 128 + wr * 64 + m * 16 + q * 4;
                ushort4 mv;
                mv.x = hh[0]; mv.y = hh[1]; mv.z = hh[2]; mv.w = hh[3];
                *(ushort4*)&Cb[(size_t)col * Nc + mcol0] = mv;
            }
        }
    }
}

// ---------------- softmax: bf16 scores (pre-scaled) in-place -> bf16 probs ---
__global__ __launch_bounds__(256) void softmax_bf16(
    bf16_t* __restrict__ S, const float* __restrict__ mask, int bc0) {
    __shared__ float sm[4];
    int gr = blockIdx.x;
    int b = (bc0 + (gr >> 11)) >> 2;
    bf16_t* row = S + (size_t)gr * CN;
    int tid = threadIdx.x;
    const float* mrow = mask + (size_t)b * CN + tid * 8;
    s16x8 v = *(const s16x8*)(row + tid * 8);
    float4 m0 = *(const float4*)(mrow);
    float4 m1 = *(const float4*)(mrow + 4);
    float x[8];
    x[0] = bf2f((unsigned short)v[0]) - m0.x * MASK_SCALE;
    x[1] = bf2f((unsigned short)v[1]) - m0.y * MASK_SCALE;
    x[2] = bf2f((unsigned short)v[2]) - m0.z * MASK_SCALE;
    x[3] = bf2f((unsigned short)v[3]) - m0.w * MASK_SCALE;
    x[4] = bf2f((unsigned short)v[4]) - m1.x * MASK_SCALE;
    x[5] = bf2f((unsigned short)v[5]) - m1.y * MASK_SCALE;
    x[6] = bf2f((unsigned short)v[6]) - m1.z * MASK_SCALE;
    x[7] = bf2f((unsigned short)v[7]) - m1.w * MASK_SCALE;
    float mx = -3.4e38f;
    #pragma unroll
    for (int i = 0; i < 8; i++) mx = fmaxf(mx, x[i]);
    mx = blockMax256(mx, sm);
    float s = 0.f;
    #pragma unroll
    for (int i = 0; i < 8; i++) { x[i] = __expf(x[i] - mx); s += x[i]; }
    s = blockSum256(s, sm);
    float inv = 1.f / s;
    s16x8 u;
    #pragma unroll
    for (int i = 0; i < 8; i++) u[i] = (short)f2bf(x[i] * inv);
    *(s16x8*)(row + tid * 8) = u;
}

// ---------------- residual + layernorm kernels (E=512, one block/row) --------
__global__ __launch_bounds__(256) void ln1_kernel(
    const bf16_t* __restrict__ src, const bf16_t* __restrict__ ao,
    const float* __restrict__ g, const float* __restrict__ be,
    bf16_t* __restrict__ o) {
    __shared__ float sm[4];
    size_t base = (size_t)blockIdx.x * CE;
    int e = threadIdx.x * 2;
    ushort2 s = *(const ushort2*)&src[base + e];
    ushort2 a = *(const ushort2*)&ao[base + e];
    float x0 = bf2f(s.x) + bf2f(a.x), x1 = bf2f(s.y) + bf2f(a.y);
    float mu = blockSum256(x0 + x1, sm) * (1.f / CE);
    float d0 = x0 - mu, d1 = x1 - mu;
    float var = blockSum256(d0 * d0 + d1 * d1, sm) * (1.f / CE);
    float rs = rsqrtf(var + EPS);
    ushort2 w;
    w.x = f2bf(d0 * rs * g[e] + be[e]);
    w.y = f2bf(d1 * rs * g[e + 1] + be[e + 1]);
    *(ushort2*)&o[base + e] = w;
}

__global__ __launch_bounds__(256) void ln2_kernel(
    const bf16_t* __restrict__ a, const bf16_t* __restrict__ b,
    const float* __restrict__ g, const float* __restrict__ be,
    float* __restrict__ o) {
    __shared__ float sm[4];
    size_t base = (size_t)blockIdx.x * CE;
    int e = threadIdx.x * 2;
    ushort2 aa = *(const ushort2*)&a[base + e];
    ushort2 bb = *(const ushort2*)&b[base + e];
    float x0 = bf2f(aa.x) + bf2f(bb.x), x1 = bf2f(aa.y) + bf2f(bb.y);
    float mu = blockSum256(x0 + x1, sm) * (1.f / CE);
    float d0 = x0 - mu, d1 = x1 - mu;
    float var = blockSum256(d0 * d0 + d1 * d1, sm) * (1.f / CE);
    float rs = rsqrtf(var + EPS);
    float2 w;
    w.x = d0 * rs * g[e] + be[e];
    w.y = d1 * rs * g[e + 1] + be[e + 1];
    *(float2*)&o[base + e] = w;
}

// ---------------- host ----------------
extern "C" void kernel_launch(void* const* d_in, const int* in_sizes, int n_in,
                              void* d_out, int out_size, void* d_ws, size_t ws_size,
                              hipStream_t stream) {
    const float* src  = (const float*)d_in[0];
    const float* mask = (const float*)d_in[1];
    const float* W1   = (const float*)d_in[2];
    const float* b1   = (const float*)d_in[3];
    const float* W2   = (const float*)d_in[4];
    const float* b2   = (const float*)d_in[5];
    const float* g1   = (const float*)d_in[6];
    const float* be1  = (const float*)d_in[7];
    const float* g2   = (const float*)d_in[8];
    const float* be2  = (const float*)d_in[9];
    float* out = (float*)d_out;
    char* ws = (char*)d_ws;

    hipFuncSetAttribute(reinterpret_cast<const void*>(&gemm256<1>), hipFuncAttributeMaxDynamicSharedMemorySize, 131072);
    hipFuncSetAttribute(reinterpret_cast<const void*>(&gemm256<3>), hipFuncAttributeMaxDynamicSharedMemorySize, 131072);
    hipFuncSetAttribute(reinterpret_cast<const void*>(&gemm256<4>), hipFuncAttributeMaxDynamicSharedMemorySize, 131072);
    hipFuncSetAttribute(reinterpret_cast<const void*>(&gemm256_sym), hipFuncAttributeMaxDynamicSharedMemorySize, 131072);

    // ---- workspace layout (MiB offsets) ----
    // [0,256)   scores/probs bf16 (all 32)  | FFN: [0,64)=src2, [64,128)=ff, [128,384)=H
    // [256,320) src_bf
    // [320,384) srcT
    // [384,448) attnO (bf16)
    // [448,452) W1T, W2T
    const size_t MB = 1024 * 1024;
    bf16_t* probs  = (bf16_t*)(ws);              // scores in-place -> probs
    bf16_t* src_bf = (bf16_t*)(ws + 256 * MB);
    bf16_t* srcT   = (bf16_t*)(ws + 320 * MB);
    bf16_t* attnO  = (bf16_t*)(ws + 384 * MB);
    bf16_t* W1T    = (bf16_t*)(ws + 448 * MB);
    bf16_t* W2T    = (bf16_t*)(ws + 450 * MB);
    bf16_t* src2   = (bf16_t*)(ws);              // overlays probs (dead after PV)
    bf16_t* ff     = (bf16_t*)(ws + 64 * MB);    // overlays probs
    bf16_t* H      = (bf16_t*)(ws + 128 * MB);   // overlays probs tail
    if (ws_size < 452 * MB) return;

    // ---- conversions (src conv + transpose fused; weights separate) ----
    cvt_transpose<<<dim3(CE / 32, CN / 32, 32), 256, 0, stream>>>(src, src_bf, srcT);
    transpose_f32_bf16<<<dim3(CF / 32, CE / 32, 1), 256, 0, stream>>>(W1, W1T, CE, CF);
    transpose_f32_bf16<<<dim3(CE / 32, CF / 32, 1), 256, 0, stream>>>(W2, W2T, CF, CE);

    // ---- attention in LLC-resident groups: sym-scores -> softmax -> PV ----
    for (int g0 = 0; g0 < CB * CC; g0 += GRP) {
        const bf16_t* srcb = src_bf + (size_t)g0 * CN * CE;
        bf16_t* probs_g = probs + (size_t)g0 * CN * CN;
        gemm256_sym<<<dim3(36, 1, GRP), 512, 131072, stream>>>(
            srcb, probs_g, SCALE, CN, CE,
            (long long)CN * CE, (long long)CN * CN);
        softmax_bf16<<<dim3(GRP * CN), 256, 0, stream>>>(probs_g, mask, g0);
        gemm256<3><<<dim3(CE / 256, CN / 256, GRP), 512, 131072, stream>>>(
            probs_g, srcT + (size_t)g0 * CE * CN, attnO + (size_t)g0 * CN * CE,
            nullptr, 1.0f, CE, CN,
            (long long)CN * CN, (long long)CE * CN, (long long)CN * CE);
    }
    ln1_kernel<<<dim3(CB * CC * CN), 256, 0, stream>>>(src_bf, attnO, g1, be1, src2);

    // ---- FFN + final LN (single chunk) ----
    gemm256<1><<<dim3(CF / 256, MCH / 256, 1), 512, 131072, stream>>>(
        src2, W1T, H, b1, 1.0f, CF, CE, 0, 0, 0);
    gemm256<4><<<dim3(CE / 256, MCH / 256, 1), 512, 131072, stream>>>(
        H, W2T, ff, b2, 1.0f, CE, CF, 0, 0, 0);
    ln2_kernel<<<dim3(MCH), 256, 0, stream>>>(src2, ff, g2, be2, out);
}

// Round 11
// 876.387 us; speedup vs baseline: 1.1687x; 1.0023x over previous
//
#include <hip/hip_runtime.h>
#include <stdint.h>

// ---------------- problem constants ----------------
constexpr int CB = 8, CC = 4, CN = 2048, CE = 512, CF = 2048;
constexpr long long TOT = (long long)CB * CC * CN * CE;
constexpr int GRP = 16;       // attention batches per LLC-resident group
constexpr int MCH = 65536;    // FFN rows (single chunk)
constexpr float SCALE = 0.04419417382415922f;  // 1/sqrt(512)
constexpr float MASK_SCALE = 5.0f;
constexpr float EPS = 1e-5f;

typedef unsigned short bf16_t;
typedef __attribute__((ext_vector_type(4))) float f32x4;
typedef __attribute__((ext_vector_type(8))) short s16x8;

#define DEV static __device__ __forceinline__

DEV unsigned short f2bf(float f) {
    unsigned u = __float_as_uint(f);
    unsigned r = (u + 0x7fffu + ((u >> 16) & 1u)) >> 16;
    return (unsigned short)r;
}
DEV float bf2f(unsigned short b) {
    return __uint_as_float(((unsigned)b) << 16);
}

typedef const __attribute__((address_space(1))) unsigned int* gptr_t;
typedef __attribute__((address_space(3))) unsigned int* lptr_t;
DEV void async16(const void* g, void* l) {
    __builtin_amdgcn_global_load_lds((gptr_t)g, (lptr_t)l, 16, 0, 0);
}

#define FULL_BAR() do { asm volatile("" ::: "memory"); __builtin_amdgcn_s_barrier(); asm volatile("" ::: "memory"); } while (0)
#define LGKM0() asm volatile("s_waitcnt lgkmcnt(0)" ::: "memory")
#define VMCNT(N_) asm volatile("s_waitcnt vmcnt(" #N_ ")" ::: "memory")

// ---------------- reductions (256-thread blocks = 4 waves) ----------------
DEV float blockSum256(float v, float* sm) {
    #pragma unroll
    for (int o = 32; o; o >>= 1) v += __shfl_xor(v, o);
    int w = threadIdx.x >> 6;
    __syncthreads();
    if ((threadIdx.x & 63) == 0) sm[w] = v;
    __syncthreads();
    return sm[0] + sm[1] + sm[2] + sm[3];
}
DEV float blockMax256(float v, float* sm) {
    #pragma unroll
    for (int o = 32; o; o >>= 1) v = fmaxf(v, __shfl_xor(v, o));
    int w = threadIdx.x >> 6;
    __syncthreads();
    if ((threadIdx.x & 63) == 0) sm[w] = v;
    __syncthreads();
    return fmaxf(fmaxf(sm[0], sm[1]), fmaxf(sm[2], sm[3]));
}

// ---------------- fused fp32->bf16 convert + batched transpose ----------------
__global__ __launch_bounds__(256) void cvt_transpose(
    const float* __restrict__ in, bf16_t* __restrict__ outN,
    bf16_t* __restrict__ outT) {
    __shared__ bf16_t tile[32][33];
    const float* inz = in + (size_t)blockIdx.z * CN * CE;
    bf16_t* oN = outN + (size_t)blockIdx.z * CN * CE;
    bf16_t* oT = outT + (size_t)blockIdx.z * CE * CN;
    int rb = blockIdx.y * 32;   // n rows
    int cb = blockIdx.x * 32;   // e cols
    int tx = threadIdx.x & 31, ty = threadIdx.x >> 5;
    #pragma unroll
    for (int i = 0; i < 32; i += 8) {
        float v = inz[(size_t)(rb + ty + i) * CE + cb + tx];
        unsigned short h = f2bf(v);
        oN[(size_t)(rb + ty + i) * CE + cb + tx] = h;
        tile[ty + i][tx] = h;
    }
    __syncthreads();
    #pragma unroll
    for (int i = 0; i < 32; i += 8)
        oT[(size_t)(cb + ty + i) * CN + rb + tx] = tile[tx][ty + i];
}

// ---------------- transpose fp32[R][C] -> bf16[C][R] (weights) ----------------
__global__ __launch_bounds__(256) void transpose_f32_bf16(
    const float* __restrict__ in, bf16_t* __restrict__ out,
    int R, int Cc) {
    __shared__ float tile[32][33];
    int rb = blockIdx.y * 32, cb = blockIdx.x * 32;
    int tx = threadIdx.x & 31, ty = threadIdx.x >> 5;
    #pragma unroll
    for (int i = 0; i < 32; i += 8)
        tile[ty + i][tx] = in[(size_t)(rb + ty + i) * Cc + cb + tx];
    __syncthreads();
    #pragma unroll
    for (int i = 0; i < 32; i += 8)
        out[(size_t)(cb + ty + i) * R + rb + tx] = f2bf(tile[tx][ty + i]);
}

// ======== shared pieces of the 256x256 GEMM ========
// bf16 in, fp32 acc, 8 waves (2Mx4N), BK=64, 128KiB dyn LDS double-buffered.
// XOR swizzle on 16B k-slots; pre-swizzled global source.
#define GEMM_CORE_DECLS() \
    extern __shared__ bf16_t lds[]; \
    bf16_t* AsL = lds; \
    bf16_t* BsL = lds + 32768; \
    const int t = threadIdx.x; \
    const int lane = t & 63, wid = t >> 6; \
    const int wr = wid >> 2, wc = wid & 3; \
    const int NT = K >> 6; \
    const int r0 = t >> 3, s0 = t & 7; \
    const int ce = ((s0 ^ (r0 & 7)) << 3); \
    const bf16_t* aP0 = Az + (size_t)(brow + r0) * K + ce; \
    const bf16_t* bP0 = Bz + (size_t)(bcol + r0) * K + ce; \
    const size_t rK64 = (size_t)64 * K; \
    const size_t h128K = rK64 * 2; \
    const int q = lane >> 4, rr0 = lane & 15, xmask = rr0 & 7; \
    s16x8 af[4][2]; \
    s16x8 bv[2][2][2]; \
    f32x4 acc[2][2][4][2] = {};

#define STAGE_A(kt_, h_) do { \
    bf16_t* d_ = AsL + ((((kt_) & 1) * 2 + (h_)) * 8192); \
    const bf16_t* s_ = aP0 + (size_t)(h_) * h128K + (size_t)(kt_) * 64; \
    async16(s_, d_ + t * 8); \
    async16(s_ + rK64, d_ + 4096 + t * 8); \
} while (0)
#define STAGE_B(kt_, h_) do { \
    bf16_t* d_ = BsL + ((((kt_) & 1) * 2 + (h_)) * 8192); \
    const bf16_t* s_ = bP0 + (size_t)(h_) * h128K + (size_t)(kt_) * 64; \
    async16(s_, d_ + t * 8); \
    async16(s_ + rK64, d_ + 4096 + t * 8); \
} while (0)
#define READ_A(ktp_, qm_) do { \
    const bf16_t* base_ = AsL + (((ktp_) * 2 + (qm_)) * 8192); \
    _Pragma("unroll") for (int m_ = 0; m_ < 4; ++m_) \
    _Pragma("unroll") for (int ks_ = 0; ks_ < 2; ++ks_) \
        af[m_][ks_] = *(const s16x8*)(base_ + (wr * 64 + m_ * 16 + rr0) * 64 + (((ks_ * 4 + q) ^ xmask) << 3)); \
} while (0)
#define READ_B(ktp_, qn_) do { \
    const bf16_t* base_ = BsL + (((ktp_) * 2 + (qn_)) * 8192); \
    _Pragma("unroll") for (int n_ = 0; n_ < 2; ++n_) \
    _Pragma("unroll") for (int ks_ = 0; ks_ < 2; ++ks_) \
        bv[qn_][n_][ks_] = *(const s16x8*)(base_ + (wc * 32 + n_ * 16 + rr0) * 64 + (((ks_ * 4 + q) ^ xmask) << 3)); \
} while (0)
#define MFMA_Q(qm_, qn_) do { \
    __builtin_amdgcn_s_setprio(1); \
    _Pragma("unroll") for (int m_ = 0; m_ < 4; ++m_) \
    _Pragma("unroll") for (int n_ = 0; n_ < 2; ++n_) \
    _Pragma("unroll") for (int ks_ = 0; ks_ < 2; ++ks_) \
        acc[qm_][qn_][m_][n_] = __builtin_amdgcn_mfma_f32_16x16x32_bf16( \
            af[m_][ks_], bv[qn_][n_][ks_], acc[qm_][qn_][m_][n_], 0, 0, 0); \
    __builtin_amdgcn_s_setprio(0); \
} while (0)

// 8-phase loop (R1-exact; best measured at long K: PV 157us/875TF @K=2048)
#define GEMM_MAIN_LOOP_8P() \
    STAGE_A(0, 0); STAGE_B(0, 0); STAGE_B(0, 1); STAGE_A(0, 1); \
    if (1 < NT) { \
        STAGE_A(1, 0); STAGE_B(1, 0); \
        VMCNT(4); \
    } else { \
        VMCNT(0); \
    } \
    FULL_BAR(); \
    for (int kt = 0; kt < NT; ++kt) { \
        const int ktp = kt & 1; \
        READ_A(ktp, 0); \
        READ_B(ktp, 0); \
        if (kt + 1 < NT) STAGE_B(kt + 1, 1); \
        FULL_BAR(); \
        LGKM0(); \
        MFMA_Q(0, 0); \
        FULL_BAR(); \
        READ_B(ktp, 1); \
        if (kt + 1 < NT) STAGE_A(kt + 1, 1); \
        FULL_BAR(); \
        LGKM0(); \
        MFMA_Q(0, 1); \
        FULL_BAR(); \
        READ_A(ktp, 1); \
        if (kt + 2 < NT) STAGE_A(kt + 2, 0); \
        FULL_BAR(); \
        LGKM0(); \
        MFMA_Q(1, 0); \
        FULL_BAR(); \
        if (kt + 2 < NT) { \
            STAGE_B(kt + 2, 0); \
            VMCNT(4); \
        } else { \
            VMCNT(0); \
        } \
        FULL_BAR(); \
        MFMA_Q(1, 1); \
        FULL_BAR(); \
    }

// 2-phase loop (R4-exact; best measured at short K: FFN1 180us @K=512)
#define GEMM_MAIN_LOOP_2P() \
    STAGE_A(0, 0); STAGE_B(0, 0); STAGE_B(0, 1); STAGE_A(0, 1); \
    VMCNT(2); \
    FULL_BAR(); \
    for (int kt = 0; kt < NT; ++kt) { \
        const int ktp = kt & 1; \
        READ_A(ktp, 0); \
        READ_B(ktp, 0); \
        READ_B(ktp, 1); \
        if (kt + 1 < NT) { \
            STAGE_A(kt + 1, 0); STAGE_B(kt + 1, 0); STAGE_B(kt + 1, 1); \
            VMCNT(6); \
        } else { \
            VMCNT(0); \
        } \
        FULL_BAR(); \
        LGKM0(); \
        MFMA_Q(0, 0); \
        MFMA_Q(0, 1); \
        READ_A(ktp, 1); \
        if (kt + 1 < NT) { \
            STAGE_A(kt + 1, 1); \
            VMCNT(2); \
        } \
        FULL_BAR(); \
        LGKM0(); \
        MFMA_Q(1, 0); \
        MFMA_Q(1, 1); \
    }

// shared epilogue: shfl col-pairing -> dword stores
#define GEMM_EPILOGUE(EPI_) do { \
    size_t cz = (size_t)bz * sC; \
    bf16_t* Cb = (bf16_t*)Cptr + cz; \
    const int lo = lane & 1; \
    _Pragma("unroll") for (int qm = 0; qm < 2; ++qm) \
    _Pragma("unroll") for (int qn = 0; qn < 2; ++qn) \
    _Pragma("unroll") for (int n = 0; n < 2; ++n) { \
        int col = bcol + qn * 128 + wc * 32 + n * 16 + rr0; \
        float bvv = ((EPI_) == 1 || (EPI_) == 4) ? bias[col] : 0.f; \
        _Pragma("unroll") for (int m = 0; m < 4; ++m) { \
            unsigned words[4]; \
            _Pragma("unroll") for (int j = 0; j < 4; ++j) { \
                float v = acc[qm][qn][m][n][j] + bvv; \
                if ((EPI_) == 1) v = fmaxf(v, 0.f); \
                if ((EPI_) == 3) v *= alpha; \
                unsigned h = f2bf(v); \
                unsigned o = (unsigned)__shfl_xor((int)h, 1); \
                words[j] = lo ? (o | (h << 16)) : (h | (o << 16)); \
            } \
            int row = brow + qm * 128 + wr * 64 + m * 16 + q * 4 + lo * 2; \
            int cp = col & ~1; \
            *(unsigned*)&Cb[(size_t)row * Nc + cp] = words[lo * 2]; \
            *(unsigned*)&Cb[(size_t)(row + 1) * Nc + cp] = words[lo * 2 + 1]; \
        } \
    } \
} while (0)

// ============ general 256x256 GEMM (8-phase, long K): PV, FFN2 ============
template <int EPI>
__global__ __launch_bounds__(512, 2) void gemm256(
    const bf16_t* __restrict__ A, const bf16_t* __restrict__ B,
    void* __restrict__ Cptr, const float* __restrict__ bias, float alpha,
    int Nc, int K, long long sA, long long sB, long long sC) {
    int bx, by, bz;
    {
        int gx = gridDim.x, gy = gridDim.y;
        int nwg = gx * gy * gridDim.z;
        int flat = blockIdx.x + gx * (blockIdx.y + gy * blockIdx.z);
        int wg = (nwg & 7) ? flat : ((flat & 7) * (nwg >> 3) + (flat >> 3));
        bx = wg % gx;
        int tmp = wg / gx;
        by = tmp % gy;
        bz = tmp / gy;
    }
    const bf16_t* Az = A + (size_t)bz * sA;
    const bf16_t* Bz = B + (size_t)bz * sB;
    const int brow = by * 256, bcol = bx * 256;

    GEMM_CORE_DECLS();
    GEMM_MAIN_LOOP_8P();
    GEMM_EPILOGUE(EPI);
}

// ============ 256x256 GEMM (2-phase, short K=512): FFN1 ============
template <int EPI>
__global__ __launch_bounds__(512, 2) void gemm256s(
    const bf16_t* __restrict__ A, const bf16_t* __restrict__ B,
    void* __restrict__ Cptr, const float* __restrict__ bias, float alpha,
    int Nc, int K, long long sA, long long sB, long long sC) {
    int bx, by, bz;
    {
        int gx = gridDim.x, gy = gridDim.y;
        int nwg = gx * gy * gridDim.z;
        int flat = blockIdx.x + gx * (blockIdx.y + gy * blockIdx.z);
        int wg = (nwg & 7) ? flat : ((flat & 7) * (nwg >> 3) + (flat >> 3));
        bx = wg % gx;
        int tmp = wg / gx;
        by = tmp % gy;
        bz = tmp / gy;
    }
    const bf16_t* Az = A + (size_t)bz * sA;
    const bf16_t* Bz = B + (size_t)bz * sB;
    const int brow = by * 256, bcol = bx * 256;

    GEMM_CORE_DECLS();
    GEMM_MAIN_LOOP_2P();
    GEMM_EPILOGUE(EPI);
}

// ============ symmetric scores GEMM (2-phase, K=512): S = a*X@X^T ============
// grid (36,1,z): lower-triangle tiles (i>=j); off-diagonal tiles mirror-store
// S[j,i] via aligned 8B ushort4 (acc j's are consecutive mirror columns).
__global__ __launch_bounds__(512, 2) void gemm256_sym(
    const bf16_t* __restrict__ A, bf16_t* __restrict__ Cptr, float alpha,
    int Nc, int K, long long sA, long long sC) {
    int bx, by, bz;
    {
        int gx = gridDim.x;                      // 36
        int nwg = gx * gridDim.z;
        int flat = blockIdx.x + gx * blockIdx.z;
        int wg = (nwg & 7) ? flat : ((flat & 7) * (nwg >> 3) + (flat >> 3));
        int tri = wg % gx;
        bz = wg / gx;
        int i = 0, b = 0;
        while (b + i + 1 <= tri) { b += i + 1; i++; }
        by = i;          // row tile
        bx = tri - b;    // col tile, bx <= by
    }
    const bf16_t* Az = A + (size_t)bz * sA;
    const bf16_t* Bz = Az;
    const int brow = by * 256, bcol = bx * 256;

    GEMM_CORE_DECLS();
    GEMM_MAIN_LOOP_2P();

    size_t cz = (size_t)bz * sC;
    bf16_t* Cb = (bf16_t*)Cptr + cz;
    const int lo = lane & 1;
    const bool mirror = (bx != by);
    #pragma unroll
    for (int qm = 0; qm < 2; ++qm)
    #pragma unroll
    for (int qn = 0; qn < 2; ++qn)
    #pragma unroll
    for (int n = 0; n < 2; ++n) {
        int col = bcol + qn * 128 + wc * 32 + n * 16 + rr0;
        #pragma unroll
        for (int m = 0; m < 4; ++m) {
            unsigned short hh[4];
            #pragma unroll
            for (int j = 0; j < 4; ++j)
                hh[j] = f2bf(acc[qm][qn][m][n][j] * alpha);
            unsigned words[4];
            #pragma unroll
            for (int j = 0; j < 4; ++j) {
                unsigned h = hh[j];
                unsigned o = (unsigned)__shfl_xor((int)h, 1);
                words[j] = lo ? (o | (h << 16)) : (h | (o << 16));
            }
            int row = brow + qm * 128 + wr * 64 + m * 16 + q * 4 + lo * 2;
            int cp = col & ~1;
            *(unsigned*)&Cb[(size_t)row * Nc + cp] = words[lo * 2];
            *(unsigned*)&Cb[(size_t)(row + 1) * Nc + cp] = words[lo * 2 + 1];
            if (mirror) {
                int mcol0 = brow + qm * 128 + wr * 64 + m * 16 + q * 4;
                ushort4 mv;
                mv.x = hh[0]; mv.y = hh[1]; mv.z = hh[2]; mv.w = hh[3];
                *(ushort4*)&Cb[(size_t)col * Nc + mcol0] = mv;
            }
        }
    }
}

// ---------------- softmax: bf16 scores (pre-scaled) in-place -> bf16 probs ---
__global__ __launch_bounds__(256) void softmax_bf16(
    bf16_t* __restrict__ S, const float* __restrict__ mask, int bc0) {
    __shared__ float sm[4];
    int gr = blockIdx.x;
    int b = (bc0 + (gr >> 11)) >> 2;
    bf16_t* row = S + (size_t)gr * CN;
    int tid = threadIdx.x;
    const float* mrow = mask + (size_t)b * CN + tid * 8;
    s16x8 v = *(const s16x8*)(row + tid * 8);
    float4 m0 = *(const float4*)(mrow);
    float4 m1 = *(const float4*)(mrow + 4);
    float x[8];
    x[0] = bf2f((unsigned short)v[0]) - m0.x * MASK_SCALE;
    x[1] = bf2f((unsigned short)v[1]) - m0.y * MASK_SCALE;
    x[2] = bf2f((unsigned short)v[2]) - m0.z * MASK_SCALE;
    x[3] = bf2f((unsigned short)v[3]) - m0.w * MASK_SCALE;
    x[4] = bf2f((unsigned short)v[4]) - m1.x * MASK_SCALE;
    x[5] = bf2f((unsigned short)v[5]) - m1.y * MASK_SCALE;
    x[6] = bf2f((unsigned short)v[6]) - m1.z * MASK_SCALE;
    x[7] = bf2f((unsigned short)v[7]) - m1.w * MASK_SCALE;
    float mx = -3.4e38f;
    #pragma unroll
    for (int i = 0; i < 8; i++) mx = fmaxf(mx, x[i]);
    mx = blockMax256(mx, sm);
    float s = 0.f;
    #pragma unroll
    for (int i = 0; i < 8; i++) { x[i] = __expf(x[i] - mx); s += x[i]; }
    s = blockSum256(s, sm);
    float inv = 1.f / s;
    s16x8 u;
    #pragma unroll
    for (int i = 0; i < 8; i++) u[i] = (short)f2bf(x[i] * inv);
    *(s16x8*)(row + tid * 8) = u;
}

// ---------------- residual + layernorm kernels (E=512, one block/row) --------
__global__ __launch_bounds__(256) void ln1_kernel(
    const bf16_t* __restrict__ src, const bf16_t* __restrict__ ao,
    const float* __restrict__ g, const float* __restrict__ be,
    bf16_t* __restrict__ o) {
    __shared__ float sm[4];
    size_t base = (size_t)blockIdx.x * CE;
    int e = threadIdx.x * 2;
    ushort2 s = *(const ushort2*)&src[base + e];
    ushort2 a = *(const ushort2*)&ao[base + e];
    float x0 = bf2f(s.x) + bf2f(a.x), x1 = bf2f(s.y) + bf2f(a.y);
    float mu = blockSum256(x0 + x1, sm) * (1.f / CE);
    float d0 = x0 - mu, d1 = x1 - mu;
    float var = blockSum256(d0 * d0 + d1 * d1, sm) * (1.f / CE);
    float rs = rsqrtf(var + EPS);
    ushort2 w;
    w.x = f2bf(d0 * rs * g[e] + be[e]);
    w.y = f2bf(d1 * rs * g[e + 1] + be[e + 1]);
    *(ushort2*)&o[base + e] = w;
}

__global__ __launch_bounds__(256) void ln2_kernel(
    const bf16_t* __restrict__ a, const bf16_t* __restrict__ b,
    const float* __restrict__ g, const float* __restrict__ be,
    float* __restrict__ o) {
    __shared__ float sm[4];
    size_t base = (size_t)blockIdx.x * CE;
    int e = threadIdx.x * 2;
    ushort2 aa = *(const ushort2*)&a[base + e];
    ushort2 bb = *(const ushort2*)&b[base + e];
    float x0 = bf2f(aa.x) + bf2f(bb.x), x1 = bf2f(aa.y) + bf2f(bb.y);
    float mu = blockSum256(x0 + x1, sm) * (1.f / CE);
    float d0 = x0 - mu, d1 = x1 - mu;
    float var = blockSum256(d0 * d0 + d1 * d1, sm) * (1.f / CE);
    float rs = rsqrtf(var + EPS);
    float2 w;
    w.x = d0 * rs * g[e] + be[e];
    w.y = d1 * rs * g[e + 1] + be[e + 1];
    *(float2*)&o[base + e] = w;
}

// ---------------- host ----------------
extern "C" void kernel_launch(void* const* d_in, const int* in_sizes, int n_in,
                              void* d_out, int out_size, void* d_ws, size_t ws_size,
                              hipStream_t stream) {
    const float* src  = (const float*)d_in[0];
    const float* mask = (const float*)d_in[1];
    const float* W1   = (const float*)d_in[2];
    const float* b1   = (const float*)d_in[3];
    const float* W2   = (const float*)d_in[4];
    const float* b2   = (const float*)d_in[5];
    const float* g1   = (const float*)d_in[6];
    const float* be1  = (const float*)d_in[7];
    const float* g2   = (const float*)d_in[8];
    const float* be2  = (const float*)d_in[9];
    float* out = (float*)d_out;
    char* ws = (char*)d_ws;

    hipFuncSetAttribute(reinterpret_cast<const void*>(&gemm256<3>), hipFuncAttributeMaxDynamicSharedMemorySize, 131072);
    hipFuncSetAttribute(reinterpret_cast<const void*>(&gemm256<4>), hipFuncAttributeMaxDynamicSharedMemorySize, 131072);
    hipFuncSetAttribute(reinterpret_cast<const void*>(&gemm256s<1>), hipFuncAttributeMaxDynamicSharedMemorySize, 131072);
    hipFuncSetAttribute(reinterpret_cast<const void*>(&gemm256_sym), hipFuncAttributeMaxDynamicSharedMemorySize, 131072);

    // ---- workspace layout (MiB offsets) ----
    // [0,256)   scores/probs bf16 (all 32)  | FFN: [0,64)=src2, [64,128)=ff, [128,384)=H
    // [256,320) src_bf
    // [320,384) srcT
    // [384,448) attnO (bf16)
    // [448,452) W1T, W2T
    const size_t MB = 1024 * 1024;
    bf16_t* probs  = (bf16_t*)(ws);              // scores in-place -> probs
    bf16_t* src_bf = (bf16_t*)(ws + 256 * MB);
    bf16_t* srcT   = (bf16_t*)(ws + 320 * MB);
    bf16_t* attnO  = (bf16_t*)(ws + 384 * MB);
    bf16_t* W1T    = (bf16_t*)(ws + 448 * MB);
    bf16_t* W2T    = (bf16_t*)(ws + 450 * MB);
    bf16_t* src2   = (bf16_t*)(ws);              // overlays probs (dead after PV)
    bf16_t* ff     = (bf16_t*)(ws + 64 * MB);    // overlays probs
    bf16_t* H      = (bf16_t*)(ws + 128 * MB);   // overlays probs tail
    if (ws_size < 452 * MB) return;

    // ---- conversions (src conv + transpose fused; weights separate) ----
    cvt_transpose<<<dim3(CE / 32, CN / 32, 32), 256, 0, stream>>>(src, src_bf, srcT);
    transpose_f32_bf16<<<dim3(CF / 32, CE / 32, 1), 256, 0, stream>>>(W1, W1T, CE, CF);
    transpose_f32_bf16<<<dim3(CE / 32, CF / 32, 1), 256, 0, stream>>>(W2, W2T, CF, CE);

    // ---- attention in LLC-resident groups: sym-scores -> softmax -> PV ----
    for (int g0 = 0; g0 < CB * CC; g0 += GRP) {
        const bf16_t* srcb = src_bf + (size_t)g0 * CN * CE;
        bf16_t* probs_g = probs + (size_t)g0 * CN * CN;
        gemm256_sym<<<dim3(36, 1, GRP), 512, 131072, stream>>>(
            srcb, probs_g, SCALE, CN, CE,
            (long long)CN * CE, (long long)CN * CN);
        softmax_bf16<<<dim3(GRP * CN), 256, 0, stream>>>(probs_g, mask, g0);
        gemm256<3><<<dim3(CE / 256, CN / 256, GRP), 512, 131072, stream>>>(
            probs_g, srcT + (size_t)g0 * CE * CN, attnO + (size_t)g0 * CN * CE,
            nullptr, 1.0f, CE, CN,
            (long long)CN * CN, (long long)CE * CN, (long long)CN * CE);
    }
    ln1_kernel<<<dim3(CB * CC * CN), 256, 0, stream>>>(src_bf, attnO, g1, be1, src2);

    // ---- FFN + final LN (single chunk) ----
    gemm256s<1><<<dim3(CF / 256, MCH / 256, 1), 512, 131072, stream>>>(
        src2, W1T, H, b1, 1.0f, CF, CE, 0, 0, 0);
    gemm256<4><<<dim3(CE / 256, MCH / 256, 1), 512, 131072, stream>>>(
        H, W2T, ff, b2, 1.0f, CE, CF, 0, 0, 0);
    ln2_kernel<<<dim3(MCH), 256, 0, stream>>>(src2, ff, g2, be2, out);
}

// Round 12
// 876.206 us; speedup vs baseline: 1.1689x; 1.0002x over previous
//
#include <hip/hip_runtime.h>
#include <stdint.h>

// ---------------- problem constants ----------------
constexpr int CB = 8, CC = 4, CN = 2048, CE = 512, CF = 2048;
constexpr long long TOT = (long long)CB * CC * CN * CE;
constexpr int GRP = 16;       // attention batches per softmax/PV group
constexpr int MCH = 65536;    // FFN rows (single chunk)
constexpr float SCALE = 0.04419417382415922f;  // 1/sqrt(512)
constexpr float MASK_SCALE = 5.0f;
constexpr float EPS = 1e-5f;

typedef unsigned short bf16_t;
typedef __attribute__((ext_vector_type(4))) float f32x4;
typedef __attribute__((ext_vector_type(8))) short s16x8;

#define DEV static __device__ __forceinline__

DEV unsigned short f2bf(float f) {
    unsigned u = __float_as_uint(f);
    unsigned r = (u + 0x7fffu + ((u >> 16) & 1u)) >> 16;
    return (unsigned short)r;
}
DEV float bf2f(unsigned short b) {
    return __uint_as_float(((unsigned)b) << 16);
}

typedef const __attribute__((address_space(1))) unsigned int* gptr_t;
typedef __attribute__((address_space(3))) unsigned int* lptr_t;
DEV void async16(const void* g, void* l) {
    __builtin_amdgcn_global_load_lds((gptr_t)g, (lptr_t)l, 16, 0, 0);
}

#define FULL_BAR() do { asm volatile("" ::: "memory"); __builtin_amdgcn_s_barrier(); asm volatile("" ::: "memory"); } while (0)
#define LGKM0() asm volatile("s_waitcnt lgkmcnt(0)" ::: "memory")
#define VMCNT(N_) asm volatile("s_waitcnt vmcnt(" #N_ ")" ::: "memory")

// ---------------- reductions (256-thread blocks = 4 waves) ----------------
DEV float blockSum256(float v, float* sm) {
    #pragma unroll
    for (int o = 32; o; o >>= 1) v += __shfl_xor(v, o);
    int w = threadIdx.x >> 6;
    __syncthreads();
    if ((threadIdx.x & 63) == 0) sm[w] = v;
    __syncthreads();
    return sm[0] + sm[1] + sm[2] + sm[3];
}
DEV float blockMax256(float v, float* sm) {
    #pragma unroll
    for (int o = 32; o; o >>= 1) v = fmaxf(v, __shfl_xor(v, o));
    int w = threadIdx.x >> 6;
    __syncthreads();
    if ((threadIdx.x & 63) == 0) sm[w] = v;
    __syncthreads();
    return fmaxf(fmaxf(sm[0], sm[1]), fmaxf(sm[2], sm[3]));
}

// ---------------- fused fp32->bf16 convert + batched transpose ----------------
__global__ __launch_bounds__(256) void cvt_transpose(
    const float* __restrict__ in, bf16_t* __restrict__ outN,
    bf16_t* __restrict__ outT) {
    __shared__ bf16_t tile[32][33];
    const float* inz = in + (size_t)blockIdx.z * CN * CE;
    bf16_t* oN = outN + (size_t)blockIdx.z * CN * CE;
    bf16_t* oT = outT + (size_t)blockIdx.z * CE * CN;
    int rb = blockIdx.y * 32;   // n rows
    int cb = blockIdx.x * 32;   // e cols
    int tx = threadIdx.x & 31, ty = threadIdx.x >> 5;
    #pragma unroll
    for (int i = 0; i < 32; i += 8) {
        float v = inz[(size_t)(rb + ty + i) * CE + cb + tx];
        unsigned short h = f2bf(v);
        oN[(size_t)(rb + ty + i) * CE + cb + tx] = h;
        tile[ty + i][tx] = h;
    }
    __syncthreads();
    #pragma unroll
    for (int i = 0; i < 32; i += 8)
        oT[(size_t)(cb + ty + i) * CN + rb + tx] = tile[tx][ty + i];
}

// ---------------- transpose fp32[R][C] -> bf16[C][R] (weights) ----------------
__global__ __launch_bounds__(256) void transpose_f32_bf16(
    const float* __restrict__ in, bf16_t* __restrict__ out,
    int R, int Cc) {
    __shared__ float tile[32][33];
    int rb = blockIdx.y * 32, cb = blockIdx.x * 32;
    int tx = threadIdx.x & 31, ty = threadIdx.x >> 5;
    #pragma unroll
    for (int i = 0; i < 32; i += 8)
        tile[ty + i][tx] = in[(size_t)(rb + ty + i) * Cc + cb + tx];
    __syncthreads();
    #pragma unroll
    for (int i = 0; i < 32; i += 8)
        out[(size_t)(cb + ty + i) * R + rb + tx] = f2bf(tile[tx][ty + i]);
}

// ======== shared pieces of the 256x256 GEMM ========
// bf16 in, fp32 acc, 8 waves (2Mx4N), BK=64, 128KiB dyn LDS double-buffered.
// XOR swizzle on 16B k-slots; pre-swizzled global source.
#define GEMM_CORE_DECLS() \
    extern __shared__ bf16_t lds[]; \
    bf16_t* AsL = lds; \
    bf16_t* BsL = lds + 32768; \
    const int t = threadIdx.x; \
    const int lane = t & 63, wid = t >> 6; \
    const int wr = wid >> 2, wc = wid & 3; \
    const int NT = K >> 6; \
    const int r0 = t >> 3, s0 = t & 7; \
    const int ce = ((s0 ^ (r0 & 7)) << 3); \
    const bf16_t* aP0 = Az + (size_t)(brow + r0) * K + ce; \
    const bf16_t* bP0 = Bz + (size_t)(bcol + r0) * K + ce; \
    const size_t rK64 = (size_t)64 * K; \
    const size_t h128K = rK64 * 2; \
    const int q = lane >> 4, rr0 = lane & 15, xmask = rr0 & 7; \
    s16x8 af[4][2]; \
    s16x8 bv[2][2][2]; \
    f32x4 acc[2][2][4][2] = {};

#define STAGE_A(kt_, h_) do { \
    bf16_t* d_ = AsL + ((((kt_) & 1) * 2 + (h_)) * 8192); \
    const bf16_t* s_ = aP0 + (size_t)(h_) * h128K + (size_t)(kt_) * 64; \
    async16(s_, d_ + t * 8); \
    async16(s_ + rK64, d_ + 4096 + t * 8); \
} while (0)
#define STAGE_B(kt_, h_) do { \
    bf16_t* d_ = BsL + ((((kt_) & 1) * 2 + (h_)) * 8192); \
    const bf16_t* s_ = bP0 + (size_t)(h_) * h128K + (size_t)(kt_) * 64; \
    async16(s_, d_ + t * 8); \
    async16(s_ + rK64, d_ + 4096 + t * 8); \
} while (0)
#define READ_A(ktp_, qm_) do { \
    const bf16_t* base_ = AsL + (((ktp_) * 2 + (qm_)) * 8192); \
    _Pragma("unroll") for (int m_ = 0; m_ < 4; ++m_) \
    _Pragma("unroll") for (int ks_ = 0; ks_ < 2; ++ks_) \
        af[m_][ks_] = *(const s16x8*)(base_ + (wr * 64 + m_ * 16 + rr0) * 64 + (((ks_ * 4 + q) ^ xmask) << 3)); \
} while (0)
#define READ_B(ktp_, qn_) do { \
    const bf16_t* base_ = BsL + (((ktp_) * 2 + (qn_)) * 8192); \
    _Pragma("unroll") for (int n_ = 0; n_ < 2; ++n_) \
    _Pragma("unroll") for (int ks_ = 0; ks_ < 2; ++ks_) \
        bv[qn_][n_][ks_] = *(const s16x8*)(base_ + (wc * 32 + n_ * 16 + rr0) * 64 + (((ks_ * 4 + q) ^ xmask) << 3)); \
} while (0)
#define MFMA_Q(qm_, qn_) do { \
    __builtin_amdgcn_s_setprio(1); \
    _Pragma("unroll") for (int m_ = 0; m_ < 4; ++m_) \
    _Pragma("unroll") for (int n_ = 0; n_ < 2; ++n_) \
    _Pragma("unroll") for (int ks_ = 0; ks_ < 2; ++ks_) \
        acc[qm_][qn_][m_][n_] = __builtin_amdgcn_mfma_f32_16x16x32_bf16( \
            af[m_][ks_], bv[qn_][n_][ks_], acc[qm_][qn_][m_][n_], 0, 0, 0); \
    __builtin_amdgcn_s_setprio(0); \
} while (0)

// 8-phase loop (R1-exact; best measured at long K: PV 157us/875TF @K=2048)
#define GEMM_MAIN_LOOP_8P() \
    STAGE_A(0, 0); STAGE_B(0, 0); STAGE_B(0, 1); STAGE_A(0, 1); \
    if (1 < NT) { \
        STAGE_A(1, 0); STAGE_B(1, 0); \
        VMCNT(4); \
    } else { \
        VMCNT(0); \
    } \
    FULL_BAR(); \
    for (int kt = 0; kt < NT; ++kt) { \
        const int ktp = kt & 1; \
        READ_A(ktp, 0); \
        READ_B(ktp, 0); \
        if (kt + 1 < NT) STAGE_B(kt + 1, 1); \
        FULL_BAR(); \
        LGKM0(); \
        MFMA_Q(0, 0); \
        FULL_BAR(); \
        READ_B(ktp, 1); \
        if (kt + 1 < NT) STAGE_A(kt + 1, 1); \
        FULL_BAR(); \
        LGKM0(); \
        MFMA_Q(0, 1); \
        FULL_BAR(); \
        READ_A(ktp, 1); \
        if (kt + 2 < NT) STAGE_A(kt + 2, 0); \
        FULL_BAR(); \
        LGKM0(); \
        MFMA_Q(1, 0); \
        FULL_BAR(); \
        if (kt + 2 < NT) { \
            STAGE_B(kt + 2, 0); \
            VMCNT(4); \
        } else { \
            VMCNT(0); \
        } \
        FULL_BAR(); \
        MFMA_Q(1, 1); \
        FULL_BAR(); \
    }

// 2-phase loop (R4-exact; best measured at short K: FFN1 180us @K=512)
#define GEMM_MAIN_LOOP_2P() \
    STAGE_A(0, 0); STAGE_B(0, 0); STAGE_B(0, 1); STAGE_A(0, 1); \
    VMCNT(2); \
    FULL_BAR(); \
    for (int kt = 0; kt < NT; ++kt) { \
        const int ktp = kt & 1; \
        READ_A(ktp, 0); \
        READ_B(ktp, 0); \
        READ_B(ktp, 1); \
        if (kt + 1 < NT) { \
            STAGE_A(kt + 1, 0); STAGE_B(kt + 1, 0); STAGE_B(kt + 1, 1); \
            VMCNT(6); \
        } else { \
            VMCNT(0); \
        } \
        FULL_BAR(); \
        LGKM0(); \
        MFMA_Q(0, 0); \
        MFMA_Q(0, 1); \
        READ_A(ktp, 1); \
        if (kt + 1 < NT) { \
            STAGE_A(kt + 1, 1); \
            VMCNT(2); \
        } \
        FULL_BAR(); \
        LGKM0(); \
        MFMA_Q(1, 0); \
        MFMA_Q(1, 1); \
    }

// shared epilogue: shfl col-pairing -> dword stores
#define GEMM_EPILOGUE(EPI_) do { \
    size_t cz = (size_t)bz * sC; \
    bf16_t* Cb = (bf16_t*)Cptr + cz; \
    const int lo = lane & 1; \
    _Pragma("unroll") for (int qm = 0; qm < 2; ++qm) \
    _Pragma("unroll") for (int qn = 0; qn < 2; ++qn) \
    _Pragma("unroll") for (int n = 0; n < 2; ++n) { \
        int col = bcol + qn * 128 + wc * 32 + n * 16 + rr0; \
        float bvv = ((EPI_) == 1 || (EPI_) == 4) ? bias[col] : 0.f; \
        _Pragma("unroll") for (int m = 0; m < 4; ++m) { \
            unsigned words[4]; \
            _Pragma("unroll") for (int j = 0; j < 4; ++j) { \
                float v = acc[qm][qn][m][n][j] + bvv; \
                if ((EPI_) == 1) v = fmaxf(v, 0.f); \
                if ((EPI_) == 3) v *= alpha; \
                unsigned h = f2bf(v); \
                unsigned o = (unsigned)__shfl_xor((int)h, 1); \
                words[j] = lo ? (o | (h << 16)) : (h | (o << 16)); \
            } \
            int row = brow + qm * 128 + wr * 64 + m * 16 + q * 4 + lo * 2; \
            int cp = col & ~1; \
            *(unsigned*)&Cb[(size_t)row * Nc + cp] = words[lo * 2]; \
            *(unsigned*)&Cb[(size_t)(row + 1) * Nc + cp] = words[lo * 2 + 1]; \
        } \
    } \
} while (0)

// ============ general 256x256 GEMM (8-phase, long K): PV, FFN2 ============
template <int EPI>
__global__ __launch_bounds__(512, 2) void gemm256(
    const bf16_t* __restrict__ A, const bf16_t* __restrict__ B,
    void* __restrict__ Cptr, const float* __restrict__ bias, float alpha,
    int Nc, int K, long long sA, long long sB, long long sC) {
    int bx, by, bz;
    {
        int gx = gridDim.x, gy = gridDim.y;
        int nwg = gx * gy * gridDim.z;
        int flat = blockIdx.x + gx * (blockIdx.y + gy * blockIdx.z);
        int wg = (nwg & 7) ? flat : ((flat & 7) * (nwg >> 3) + (flat >> 3));
        bx = wg % gx;
        int tmp = wg / gx;
        by = tmp % gy;
        bz = tmp / gy;
    }
    const bf16_t* Az = A + (size_t)bz * sA;
    const bf16_t* Bz = B + (size_t)bz * sB;
    const int brow = by * 256, bcol = bx * 256;

    GEMM_CORE_DECLS();
    GEMM_MAIN_LOOP_8P();
    GEMM_EPILOGUE(EPI);
}

// ============ 256x256 GEMM (2-phase, short K=512): FFN1 ============
template <int EPI>
__global__ __launch_bounds__(512, 2) void gemm256s(
    const bf16_t* __restrict__ A, const bf16_t* __restrict__ B,
    void* __restrict__ Cptr, const float* __restrict__ bias, float alpha,
    int Nc, int K, long long sA, long long sB, long long sC) {
    int bx, by, bz;
    {
        int gx = gridDim.x, gy = gridDim.y;
        int nwg = gx * gy * gridDim.z;
        int flat = blockIdx.x + gx * (blockIdx.y + gy * blockIdx.z);
        int wg = (nwg & 7) ? flat : ((flat & 7) * (nwg >> 3) + (flat >> 3));
        bx = wg % gx;
        int tmp = wg / gx;
        by = tmp % gy;
        bz = tmp / gy;
    }
    const bf16_t* Az = A + (size_t)bz * sA;
    const bf16_t* Bz = B + (size_t)bz * sB;
    const int brow = by * 256, bcol = bx * 256;

    GEMM_CORE_DECLS();
    GEMM_MAIN_LOOP_2P();
    GEMM_EPILOGUE(EPI);
}

// ============ symmetric scores GEMM (2-phase, K=512): S = a*X@X^T ============
// Single dispatch for ALL 32 batches (grid 36x1x32 = 1152 blocks: one 4.5-round
// launch instead of two 2.25-round launches -> tail-round waste paid once).
// Lower-triangle tiles (i>=j); off-diagonal tiles mirror-store S[j,i] via
// aligned 8B ushort4 (acc j's are consecutive mirror columns).
__global__ __launch_bounds__(512, 2) void gemm256_sym(
    const bf16_t* __restrict__ A, bf16_t* __restrict__ Cptr, float alpha,
    int Nc, int K, long long sA, long long sC) {
    int bx, by, bz;
    {
        int gx = gridDim.x;                      // 36
        int nwg = gx * gridDim.z;
        int flat = blockIdx.x + gx * blockIdx.z;
        int wg = (nwg & 7) ? flat : ((flat & 7) * (nwg >> 3) + (flat >> 3));
        int tri = wg % gx;
        bz = wg / gx;
        int i = 0, b = 0;
        while (b + i + 1 <= tri) { b += i + 1; i++; }
        by = i;          // row tile
        bx = tri - b;    // col tile, bx <= by
    }
    const bf16_t* Az = A + (size_t)bz * sA;
    const bf16_t* Bz = Az;
    const int brow = by * 256, bcol = bx * 256;

    GEMM_CORE_DECLS();
    GEMM_MAIN_LOOP_2P();

    size_t cz = (size_t)bz * sC;
    bf16_t* Cb = (bf16_t*)Cptr + cz;
    const int lo = lane & 1;
    const bool mirror = (bx != by);
    #pragma unroll
    for (int qm = 0; qm < 2; ++qm)
    #pragma unroll
    for (int qn = 0; qn < 2; ++qn)
    #pragma unroll
    for (int n = 0; n < 2; ++n) {
        int col = bcol + qn * 128 + wc * 32 + n * 16 + rr0;
        #pragma unroll
        for (int m = 0; m < 4; ++m) {
            unsigned short hh[4];
            #pragma unroll
            for (int j = 0; j < 4; ++j)
                hh[j] = f2bf(acc[qm][qn][m][n][j] * alpha);
            unsigned words[4];
            #pragma unroll
            for (int j = 0; j < 4; ++j) {
                unsigned h = hh[j];
                unsigned o = (unsigned)__shfl_xor((int)h, 1);
                words[j] = lo ? (o | (h << 16)) : (h | (o << 16));
            }
            int row = brow + qm * 128 + wr * 64 + m * 16 + q * 4 + lo * 2;
            int cp = col & ~1;
            *(unsigned*)&Cb[(size_t)row * Nc + cp] = words[lo * 2];
            *(unsigned*)&Cb[(size_t)(row + 1) * Nc + cp] = words[lo * 2 + 1];
            if (mirror) {
                int mcol0 = brow + qm * 128 + wr * 64 + m * 16 + q * 4;
                ushort4 mv;
                mv.x = hh[0]; mv.y = hh[1]; mv.z = hh[2]; mv.w = hh[3];
                *(ushort4*)&Cb[(size_t)col * Nc + mcol0] = mv;
            }
        }
    }
}

// ---------------- softmax: bf16 scores (pre-scaled) in-place -> bf16 probs ---
__global__ __launch_bounds__(256) void softmax_bf16(
    bf16_t* __restrict__ S, const float* __restrict__ mask, int bc0) {
    __shared__ float sm[4];
    int gr = blockIdx.x;
    int b = (bc0 + (gr >> 11)) >> 2;
    bf16_t* row = S + (size_t)gr * CN;
    int tid = threadIdx.x;
    const float* mrow = mask + (size_t)b * CN + tid * 8;
    s16x8 v = *(const s16x8*)(row + tid * 8);
    float4 m0 = *(const float4*)(mrow);
    float4 m1 = *(const float4*)(mrow + 4);
    float x[8];
    x[0] = bf2f((unsigned short)v[0]) - m0.x * MASK_SCALE;
    x[1] = bf2f((unsigned short)v[1]) - m0.y * MASK_SCALE;
    x[2] = bf2f((unsigned short)v[2]) - m0.z * MASK_SCALE;
    x[3] = bf2f((unsigned short)v[3]) - m0.w * MASK_SCALE;
    x[4] = bf2f((unsigned short)v[4]) - m1.x * MASK_SCALE;
    x[5] = bf2f((unsigned short)v[5]) - m1.y * MASK_SCALE;
    x[6] = bf2f((unsigned short)v[6]) - m1.z * MASK_SCALE;
    x[7] = bf2f((unsigned short)v[7]) - m1.w * MASK_SCALE;
    float mx = -3.4e38f;
    #pragma unroll
    for (int i = 0; i < 8; i++) mx = fmaxf(mx, x[i]);
    mx = blockMax256(mx, sm);
    float s = 0.f;
    #pragma unroll
    for (int i = 0; i < 8; i++) { x[i] = __expf(x[i] - mx); s += x[i]; }
    s = blockSum256(s, sm);
    float inv = 1.f / s;
    s16x8 u;
    #pragma unroll
    for (int i = 0; i < 8; i++) u[i] = (short)f2bf(x[i] * inv);
    *(s16x8*)(row + tid * 8) = u;
}

// ---------------- residual + layernorm kernels (E=512, one block/row) --------
__global__ __launch_bounds__(256) void ln1_kernel(
    const bf16_t* __restrict__ src, const bf16_t* __restrict__ ao,
    const float* __restrict__ g, const float* __restrict__ be,
    bf16_t* __restrict__ o) {
    __shared__ float sm[4];
    size_t base = (size_t)blockIdx.x * CE;
    int e = threadIdx.x * 2;
    ushort2 s = *(const ushort2*)&src[base + e];
    ushort2 a = *(const ushort2*)&ao[base + e];
    float x0 = bf2f(s.x) + bf2f(a.x), x1 = bf2f(s.y) + bf2f(a.y);
    float mu = blockSum256(x0 + x1, sm) * (1.f / CE);
    float d0 = x0 - mu, d1 = x1 - mu;
    float var = blockSum256(d0 * d0 + d1 * d1, sm) * (1.f / CE);
    float rs = rsqrtf(var + EPS);
    ushort2 w;
    w.x = f2bf(d0 * rs * g[e] + be[e]);
    w.y = f2bf(d1 * rs * g[e + 1] + be[e + 1]);
    *(ushort2*)&o[base + e] = w;
}

__global__ __launch_bounds__(256) void ln2_kernel(
    const bf16_t* __restrict__ a, const bf16_t* __restrict__ b,
    const float* __restrict__ g, const float* __restrict__ be,
    float* __restrict__ o) {
    __shared__ float sm[4];
    size_t base = (size_t)blockIdx.x * CE;
    int e = threadIdx.x * 2;
    ushort2 aa = *(const ushort2*)&a[base + e];
    ushort2 bb = *(const ushort2*)&b[base + e];
    float x0 = bf2f(aa.x) + bf2f(bb.x), x1 = bf2f(aa.y) + bf2f(bb.y);
    float mu = blockSum256(x0 + x1, sm) * (1.f / CE);
    float d0 = x0 - mu, d1 = x1 - mu;
    float var = blockSum256(d0 * d0 + d1 * d1, sm) * (1.f / CE);
    float rs = rsqrtf(var + EPS);
    float2 w;
    w.x = d0 * rs * g[e] + be[e];
    w.y = d1 * rs * g[e + 1] + be[e + 1];
    *(float2*)&o[base + e] = w;
}

// ---------------- host ----------------
extern "C" void kernel_launch(void* const* d_in, const int* in_sizes, int n_in,
                              void* d_out, int out_size, void* d_ws, size_t ws_size,
                              hipStream_t stream) {
    const float* src  = (const float*)d_in[0];
    const float* mask = (const float*)d_in[1];
    const float* W1   = (const float*)d_in[2];
    const float* b1   = (const float*)d_in[3];
    const float* W2   = (const float*)d_in[4];
    const float* b2   = (const float*)d_in[5];
    const float* g1   = (const float*)d_in[6];
    const float* be1  = (const float*)d_in[7];
    const float* g2   = (const float*)d_in[8];
    const float* be2  = (const float*)d_in[9];
    float* out = (float*)d_out;
    char* ws = (char*)d_ws;

    hipFuncSetAttribute(reinterpret_cast<const void*>(&gemm256<3>), hipFuncAttributeMaxDynamicSharedMemorySize, 131072);
    hipFuncSetAttribute(reinterpret_cast<const void*>(&gemm256<4>), hipFuncAttributeMaxDynamicSharedMemorySize, 131072);
    hipFuncSetAttribute(reinterpret_cast<const void*>(&gemm256s<1>), hipFuncAttributeMaxDynamicSharedMemorySize, 131072);
    hipFuncSetAttribute(reinterpret_cast<const void*>(&gemm256_sym), hipFuncAttributeMaxDynamicSharedMemorySize, 131072);

    // ---- workspace layout (MiB offsets) ----
    // [0,256)   scores/probs bf16 (all 32)  | FFN: [0,64)=src2, [64,128)=ff, [128,384)=H
    // [256,320) src_bf
    // [320,384) srcT
    // [384,448) attnO (bf16)
    // [448,452) W1T, W2T
    const size_t MB = 1024 * 1024;
    bf16_t* probs  = (bf16_t*)(ws);              // scores in-place -> probs
    bf16_t* src_bf = (bf16_t*)(ws + 256 * MB);
    bf16_t* srcT   = (bf16_t*)(ws + 320 * MB);
    bf16_t* attnO  = (bf16_t*)(ws + 384 * MB);
    bf16_t* W1T    = (bf16_t*)(ws + 448 * MB);
    bf16_t* W2T    = (bf16_t*)(ws + 450 * MB);
    bf16_t* src2   = (bf16_t*)(ws);              // overlays probs (dead after PV)
    bf16_t* ff     = (bf16_t*)(ws + 64 * MB);    // overlays probs
    bf16_t* H      = (bf16_t*)(ws + 128 * MB);   // overlays probs tail
    if (ws_size < 452 * MB) return;

    // ---- conversions (src conv + transpose fused; weights separate) ----
    cvt_transpose<<<dim3(CE / 32, CN / 32, 32), 256, 0, stream>>>(src, src_bf, srcT);
    transpose_f32_bf16<<<dim3(CF / 32, CE / 32, 1), 256, 0, stream>>>(W1, W1T, CE, CF);
    transpose_f32_bf16<<<dim3(CE / 32, CF / 32, 1), 256, 0, stream>>>(W2, W2T, CF, CE);

    // ---- attention: ONE sym-scores dispatch (all 32), then per-group
    //      softmax -> PV (probs group stays L3-warm between the two) ----
    gemm256_sym<<<dim3(36, 1, 32), 512, 131072, stream>>>(
        src_bf, probs, SCALE, CN, CE,
        (long long)CN * CE, (long long)CN * CN);
    for (int g0 = 0; g0 < CB * CC; g0 += GRP) {
        bf16_t* probs_g = probs + (size_t)g0 * CN * CN;
        softmax_bf16<<<dim3(GRP * CN), 256, 0, stream>>>(probs_g, mask, g0);
        gemm256<3><<<dim3(CE / 256, CN / 256, GRP), 512, 131072, stream>>>(
            probs_g, srcT + (size_t)g0 * CE * CN, attnO + (size_t)g0 * CN * CE,
            nullptr, 1.0f, CE, CN,
            (long long)CN * CN, (long long)CE * CN, (long long)CN * CE);
    }
    ln1_kernel<<<dim3(CB * CC * CN), 256, 0, stream>>>(src_bf, attnO, g1, be1, src2);

    // ---- FFN + final LN (single chunk) ----
    gemm256s<1><<<dim3(CF / 256, MCH / 256, 1), 512, 131072, stream>>>(
        src2, W1T, H, b1, 1.0f, CF, CE, 0, 0, 0);
    gemm256<4><<<dim3(CE / 256, MCH / 256, 1), 512, 131072, stream>>>(
        H, W2T, ff, b2, 1.0f, CE, CF, 0, 0, 0);
    ln2_kernel<<<dim3(MCH), 256, 0, stream>>>(src2, ff, g2, be2, out);
}

// Round 13
// 855.665 us; speedup vs baseline: 1.1970x; 1.0240x over previous
//
#include <hip/hip_runtime.h>
#include <stdint.h>

// ---------------- problem constants ----------------
constexpr int CB = 8, CC = 4, CN = 2048, CE = 512, CF = 2048;
constexpr long long TOT = (long long)CB * CC * CN * CE;
constexpr int GRP = 16;       // attention batches per softmax/PV group
constexpr int MCH = 65536;    // FFN rows (single chunk)
constexpr float SCALE = 0.04419417382415922f;  // 1/sqrt(512)
constexpr float MASK_SCALE = 5.0f;
constexpr float EPS = 1e-5f;

typedef unsigned short bf16_t;
typedef __attribute__((ext_vector_type(4))) float f32x4;
typedef __attribute__((ext_vector_type(8))) short s16x8;

#define DEV static __device__ __forceinline__

DEV unsigned short f2bf(float f) {
    unsigned u = __float_as_uint(f);
    unsigned r = (u + 0x7fffu + ((u >> 16) & 1u)) >> 16;
    return (unsigned short)r;
}
DEV float bf2f(unsigned short b) {
    return __uint_as_float(((unsigned)b) << 16);
}

typedef const __attribute__((address_space(1))) unsigned int* gptr_t;
typedef __attribute__((address_space(3))) unsigned int* lptr_t;
DEV void async16(const void* g, void* l) {
    __builtin_amdgcn_global_load_lds((gptr_t)g, (lptr_t)l, 16, 0, 0);
}

#define FULL_BAR() do { asm volatile("" ::: "memory"); __builtin_amdgcn_s_barrier(); asm volatile("" ::: "memory"); } while (0)
#define LGKM0() asm volatile("s_waitcnt lgkmcnt(0)" ::: "memory")
#define VMCNT(N_) asm volatile("s_waitcnt vmcnt(" #N_ ")" ::: "memory")

// ---------------- reductions (256-thread blocks = 4 waves) ----------------
DEV float blockSum256(float v, float* sm) {
    #pragma unroll
    for (int o = 32; o; o >>= 1) v += __shfl_xor(v, o);
    int w = threadIdx.x >> 6;
    __syncthreads();
    if ((threadIdx.x & 63) == 0) sm[w] = v;
    __syncthreads();
    return sm[0] + sm[1] + sm[2] + sm[3];
}
DEV float blockMax256(float v, float* sm) {
    #pragma unroll
    for (int o = 32; o; o >>= 1) v = fmaxf(v, __shfl_xor(v, o));
    int w = threadIdx.x >> 6;
    __syncthreads();
    if ((threadIdx.x & 63) == 0) sm[w] = v;
    __syncthreads();
    return fmaxf(fmaxf(sm[0], sm[1]), fmaxf(sm[2], sm[3]));
}

// ---------------- fused fp32->bf16 convert + batched transpose ----------------
__global__ __launch_bounds__(256) void cvt_transpose(
    const float* __restrict__ in, bf16_t* __restrict__ outN,
    bf16_t* __restrict__ outT) {
    __shared__ bf16_t tile[32][33];
    const float* inz = in + (size_t)blockIdx.z * CN * CE;
    bf16_t* oN = outN + (size_t)blockIdx.z * CN * CE;
    bf16_t* oT = outT + (size_t)blockIdx.z * CE * CN;
    int rb = blockIdx.y * 32;   // n rows
    int cb = blockIdx.x * 32;   // e cols
    int tx = threadIdx.x & 31, ty = threadIdx.x >> 5;
    #pragma unroll
    for (int i = 0; i < 32; i += 8) {
        float v = inz[(size_t)(rb + ty + i) * CE + cb + tx];
        unsigned short h = f2bf(v);
        oN[(size_t)(rb + ty + i) * CE + cb + tx] = h;
        tile[ty + i][tx] = h;
    }
    __syncthreads();
    #pragma unroll
    for (int i = 0; i < 32; i += 8)
        oT[(size_t)(cb + ty + i) * CN + rb + tx] = tile[tx][ty + i];
}

// ---------------- transpose fp32[R][C] -> bf16[C][R] (weights) ----------------
__global__ __launch_bounds__(256) void transpose_f32_bf16(
    const float* __restrict__ in, bf16_t* __restrict__ out,
    int R, int Cc) {
    __shared__ float tile[32][33];
    int rb = blockIdx.y * 32, cb = blockIdx.x * 32;
    int tx = threadIdx.x & 31, ty = threadIdx.x >> 5;
    #pragma unroll
    for (int i = 0; i < 32; i += 8)
        tile[ty + i][tx] = in[(size_t)(rb + ty + i) * Cc + cb + tx];
    __syncthreads();
    #pragma unroll
    for (int i = 0; i < 32; i += 8)
        out[(size_t)(cb + ty + i) * R + rb + tx] = f2bf(tile[tx][ty + i]);
}

// ======== shared pieces of the 256x256 GEMM ========
// bf16 in, fp32 acc, 8 waves (2Mx4N), BK=64, 128KiB dyn LDS double-buffered.
// XOR swizzle on 16B k-slots; pre-swizzled global source.
#define GEMM_CORE_DECLS() \
    extern __shared__ bf16_t lds[]; \
    bf16_t* AsL = lds; \
    bf16_t* BsL = lds + 32768; \
    const int t = threadIdx.x; \
    const int lane = t & 63, wid = t >> 6; \
    const int wr = wid >> 2, wc = wid & 3; \
    const int NT = K >> 6; \
    const int r0 = t >> 3, s0 = t & 7; \
    const int ce = ((s0 ^ (r0 & 7)) << 3); \
    const bf16_t* aP0 = Az + (size_t)(brow + r0) * K + ce; \
    const bf16_t* bP0 = Bz + (size_t)(bcol + r0) * K + ce; \
    const size_t rK64 = (size_t)64 * K; \
    const size_t h128K = rK64 * 2; \
    const int q = lane >> 4, rr0 = lane & 15, xmask = rr0 & 7; \
    s16x8 af[4][2]; \
    s16x8 bv[2][2][2]; \
    f32x4 acc[2][2][4][2] = {};

#define STAGE_A(kt_, h_) do { \
    bf16_t* d_ = AsL + ((((kt_) & 1) * 2 + (h_)) * 8192); \
    const bf16_t* s_ = aP0 + (size_t)(h_) * h128K + (size_t)(kt_) * 64; \
    async16(s_, d_ + t * 8); \
    async16(s_ + rK64, d_ + 4096 + t * 8); \
} while (0)
#define STAGE_B(kt_, h_) do { \
    bf16_t* d_ = BsL + ((((kt_) & 1) * 2 + (h_)) * 8192); \
    const bf16_t* s_ = bP0 + (size_t)(h_) * h128K + (size_t)(kt_) * 64; \
    async16(s_, d_ + t * 8); \
    async16(s_ + rK64, d_ + 4096 + t * 8); \
} while (0)
#define READ_A(ktp_, qm_) do { \
    const bf16_t* base_ = AsL + (((ktp_) * 2 + (qm_)) * 8192); \
    _Pragma("unroll") for (int m_ = 0; m_ < 4; ++m_) \
    _Pragma("unroll") for (int ks_ = 0; ks_ < 2; ++ks_) \
        af[m_][ks_] = *(const s16x8*)(base_ + (wr * 64 + m_ * 16 + rr0) * 64 + (((ks_ * 4 + q) ^ xmask) << 3)); \
} while (0)
#define READ_B(ktp_, qn_) do { \
    const bf16_t* base_ = BsL + (((ktp_) * 2 + (qn_)) * 8192); \
    _Pragma("unroll") for (int n_ = 0; n_ < 2; ++n_) \
    _Pragma("unroll") for (int ks_ = 0; ks_ < 2; ++ks_) \
        bv[qn_][n_][ks_] = *(const s16x8*)(base_ + (wc * 32 + n_ * 16 + rr0) * 64 + (((ks_ * 4 + q) ^ xmask) << 3)); \
} while (0)
#define MFMA_Q(qm_, qn_) do { \
    __builtin_amdgcn_s_setprio(1); \
    _Pragma("unroll") for (int m_ = 0; m_ < 4; ++m_) \
    _Pragma("unroll") for (int n_ = 0; n_ < 2; ++n_) \
    _Pragma("unroll") for (int ks_ = 0; ks_ < 2; ++ks_) \
        acc[qm_][qn_][m_][n_] = __builtin_amdgcn_mfma_f32_16x16x32_bf16( \
            af[m_][ks_], bv[qn_][n_][ks_], acc[qm_][qn_][m_][n_], 0, 0, 0); \
    __builtin_amdgcn_s_setprio(0); \
} while (0)

// 8-phase loop (R1-exact; best measured at long K: PV 157us/875TF @K=2048)
#define GEMM_MAIN_LOOP_8P() \
    STAGE_A(0, 0); STAGE_B(0, 0); STAGE_B(0, 1); STAGE_A(0, 1); \
    if (1 < NT) { \
        STAGE_A(1, 0); STAGE_B(1, 0); \
        VMCNT(4); \
    } else { \
        VMCNT(0); \
    } \
    FULL_BAR(); \
    for (int kt = 0; kt < NT; ++kt) { \
        const int ktp = kt & 1; \
        READ_A(ktp, 0); \
        READ_B(ktp, 0); \
        if (kt + 1 < NT) STAGE_B(kt + 1, 1); \
        FULL_BAR(); \
        LGKM0(); \
        MFMA_Q(0, 0); \
        FULL_BAR(); \
        READ_B(ktp, 1); \
        if (kt + 1 < NT) STAGE_A(kt + 1, 1); \
        FULL_BAR(); \
        LGKM0(); \
        MFMA_Q(0, 1); \
        FULL_BAR(); \
        READ_A(ktp, 1); \
        if (kt + 2 < NT) STAGE_A(kt + 2, 0); \
        FULL_BAR(); \
        LGKM0(); \
        MFMA_Q(1, 0); \
        FULL_BAR(); \
        if (kt + 2 < NT) { \
            STAGE_B(kt + 2, 0); \
            VMCNT(4); \
        } else { \
            VMCNT(0); \
        } \
        FULL_BAR(); \
        MFMA_Q(1, 1); \
        FULL_BAR(); \
    }

// 2-phase loop (R4-exact; best measured at short K: FFN1 180us @K=512)
#define GEMM_MAIN_LOOP_2P() \
    STAGE_A(0, 0); STAGE_B(0, 0); STAGE_B(0, 1); STAGE_A(0, 1); \
    VMCNT(2); \
    FULL_BAR(); \
    for (int kt = 0; kt < NT; ++kt) { \
        const int ktp = kt & 1; \
        READ_A(ktp, 0); \
        READ_B(ktp, 0); \
        READ_B(ktp, 1); \
        if (kt + 1 < NT) { \
            STAGE_A(kt + 1, 0); STAGE_B(kt + 1, 0); STAGE_B(kt + 1, 1); \
            VMCNT(6); \
        } else { \
            VMCNT(0); \
        } \
        FULL_BAR(); \
        LGKM0(); \
        MFMA_Q(0, 0); \
        MFMA_Q(0, 1); \
        READ_A(ktp, 1); \
        if (kt + 1 < NT) { \
            STAGE_A(kt + 1, 1); \
            VMCNT(2); \
        } \
        FULL_BAR(); \
        LGKM0(); \
        MFMA_Q(1, 0); \
        MFMA_Q(1, 1); \
    }

// shared epilogue: R4-exact direct scattered 2B stores (L2 coalesces within
// the wave's 64B lines: measured WRITE_SIZE identical to paired stores, and
// avoids 64 shfl DS-pipe ops + packing ALU per thread).
#define GEMM_EPILOGUE(EPI_) do { \
    size_t cz = (size_t)bz * sC; \
    bf16_t* Cb = (bf16_t*)Cptr + cz; \
    _Pragma("unroll") for (int qm = 0; qm < 2; ++qm) \
    _Pragma("unroll") for (int qn = 0; qn < 2; ++qn) \
    _Pragma("unroll") for (int n = 0; n < 2; ++n) { \
        int col = bcol + qn * 128 + wc * 32 + n * 16 + rr0; \
        float bvv = ((EPI_) == 1 || (EPI_) == 4) ? bias[col] : 0.f; \
        _Pragma("unroll") for (int m = 0; m < 4; ++m) { \
            _Pragma("unroll") for (int j = 0; j < 4; ++j) { \
                float v = acc[qm][qn][m][n][j] + bvv; \
                if ((EPI_) == 1) v = fmaxf(v, 0.f); \
                if ((EPI_) == 3) v *= alpha; \
                int row = brow + qm * 128 + wr * 64 + m * 16 + q * 4 + j; \
                Cb[(size_t)row * Nc + col] = f2bf(v); \
            } \
        } \
    } \
} while (0)

// ============ general 256x256 GEMM (8-phase, long K): PV, FFN2 ============
template <int EPI>
__global__ __launch_bounds__(512, 2) void gemm256(
    const bf16_t* __restrict__ A, const bf16_t* __restrict__ B,
    void* __restrict__ Cptr, const float* __restrict__ bias, float alpha,
    int Nc, int K, long long sA, long long sB, long long sC) {
    int bx, by, bz;
    {
        int gx = gridDim.x, gy = gridDim.y;
        int nwg = gx * gy * gridDim.z;
        int flat = blockIdx.x + gx * (blockIdx.y + gy * blockIdx.z);
        int wg = (nwg & 7) ? flat : ((flat & 7) * (nwg >> 3) + (flat >> 3));
        bx = wg % gx;
        int tmp = wg / gx;
        by = tmp % gy;
        bz = tmp / gy;
    }
    const bf16_t* Az = A + (size_t)bz * sA;
    const bf16_t* Bz = B + (size_t)bz * sB;
    const int brow = by * 256, bcol = bx * 256;

    GEMM_CORE_DECLS();
    GEMM_MAIN_LOOP_8P();
    GEMM_EPILOGUE(EPI);
}

// ============ 256x256 GEMM (2-phase, short K=512): FFN1 ============
template <int EPI>
__global__ __launch_bounds__(512, 2) void gemm256s(
    const bf16_t* __restrict__ A, const bf16_t* __restrict__ B,
    void* __restrict__ Cptr, const float* __restrict__ bias, float alpha,
    int Nc, int K, long long sA, long long sB, long long sC) {
    int bx, by, bz;
    {
        int gx = gridDim.x, gy = gridDim.y;
        int nwg = gx * gy * gridDim.z;
        int flat = blockIdx.x + gx * (blockIdx.y + gy * blockIdx.z);
        int wg = (nwg & 7) ? flat : ((flat & 7) * (nwg >> 3) + (flat >> 3));
        bx = wg % gx;
        int tmp = wg / gx;
        by = tmp % gy;
        bz = tmp / gy;
    }
    const bf16_t* Az = A + (size_t)bz * sA;
    const bf16_t* Bz = B + (size_t)bz * sB;
    const int brow = by * 256, bcol = bx * 256;

    GEMM_CORE_DECLS();
    GEMM_MAIN_LOOP_2P();
    GEMM_EPILOGUE(EPI);
}

// ============ symmetric scores GEMM (2-phase, K=512): S = a*X@X^T ============
// Single dispatch for all 32 batches (grid 36x1x32). Lower-triangle tiles
// (i>=j); off-diagonal tiles mirror-store S[j,i] via aligned 8B ushort4
// (acc j's are consecutive mirror columns).
__global__ __launch_bounds__(512, 2) void gemm256_sym(
    const bf16_t* __restrict__ A, bf16_t* __restrict__ Cptr, float alpha,
    int Nc, int K, long long sA, long long sC) {
    int bx, by, bz;
    {
        int gx = gridDim.x;                      // 36
        int nwg = gx * gridDim.z;
        int flat = blockIdx.x + gx * blockIdx.z;
        int wg = (nwg & 7) ? flat : ((flat & 7) * (nwg >> 3) + (flat >> 3));
        int tri = wg % gx;
        bz = wg / gx;
        int i = 0, b = 0;
        while (b + i + 1 <= tri) { b += i + 1; i++; }
        by = i;          // row tile
        bx = tri - b;    // col tile, bx <= by
    }
    const bf16_t* Az = A + (size_t)bz * sA;
    const bf16_t* Bz = Az;
    const int brow = by * 256, bcol = bx * 256;

    GEMM_CORE_DECLS();
    GEMM_MAIN_LOOP_2P();

    size_t cz = (size_t)bz * sC;
    bf16_t* Cb = (bf16_t*)Cptr + cz;
    const bool mirror = (bx != by);
    #pragma unroll
    for (int qm = 0; qm < 2; ++qm)
    #pragma unroll
    for (int qn = 0; qn < 2; ++qn)
    #pragma unroll
    for (int n = 0; n < 2; ++n) {
        int col = bcol + qn * 128 + wc * 32 + n * 16 + rr0;
        #pragma unroll
        for (int m = 0; m < 4; ++m) {
            unsigned short hh[4];
            int row0 = brow + qm * 128 + wr * 64 + m * 16 + q * 4;
            #pragma unroll
            for (int j = 0; j < 4; ++j) {
                hh[j] = f2bf(acc[qm][qn][m][n][j] * alpha);
                Cb[(size_t)(row0 + j) * Nc + col] = hh[j];
            }
            if (mirror) {
                ushort4 mv;
                mv.x = hh[0]; mv.y = hh[1]; mv.z = hh[2]; mv.w = hh[3];
                *(ushort4*)&Cb[(size_t)col * Nc + row0] = mv;
            }
        }
    }
}

// ---------------- softmax: bf16 scores (pre-scaled) in-place -> bf16 probs ---
__global__ __launch_bounds__(256) void softmax_bf16(
    bf16_t* __restrict__ S, const float* __restrict__ mask, int bc0) {
    __shared__ float sm[4];
    int gr = blockIdx.x;
    int b = (bc0 + (gr >> 11)) >> 2;
    bf16_t* row = S + (size_t)gr * CN;
    int tid = threadIdx.x;
    const float* mrow = mask + (size_t)b * CN + tid * 8;
    s16x8 v = *(const s16x8*)(row + tid * 8);
    float4 m0 = *(const float4*)(mrow);
    float4 m1 = *(const float4*)(mrow + 4);
    float x[8];
    x[0] = bf2f((unsigned short)v[0]) - m0.x * MASK_SCALE;
    x[1] = bf2f((unsigned short)v[1]) - m0.y * MASK_SCALE;
    x[2] = bf2f((unsigned short)v[2]) - m0.z * MASK_SCALE;
    x[3] = bf2f((unsigned short)v[3]) - m0.w * MASK_SCALE;
    x[4] = bf2f((unsigned short)v[4]) - m1.x * MASK_SCALE;
    x[5] = bf2f((unsigned short)v[5]) - m1.y * MASK_SCALE;
    x[6] = bf2f((unsigned short)v[6]) - m1.z * MASK_SCALE;
    x[7] = bf2f((unsigned short)v[7]) - m1.w * MASK_SCALE;
    float mx = -3.4e38f;
    #pragma unroll
    for (int i = 0; i < 8; i++) mx = fmaxf(mx, x[i]);
    mx = blockMax256(mx, sm);
    float s = 0.f;
    #pragma unroll
    for (int i = 0; i < 8; i++) { x[i] = __expf(x[i] - mx); s += x[i]; }
    s = blockSum256(s, sm);
    float inv = 1.f / s;
    s16x8 u;
    #pragma unroll
    for (int i = 0; i < 8; i++) u[i] = (short)f2bf(x[i] * inv);
    *(s16x8*)(row + tid * 8) = u;
}

// ---------------- residual + layernorm kernels (E=512, one block/row) --------
__global__ __launch_bounds__(256) void ln1_kernel(
    const bf16_t* __restrict__ src, const bf16_t* __restrict__ ao,
    const float* __restrict__ g, const float* __restrict__ be,
    bf16_t* __restrict__ o) {
    __shared__ float sm[4];
    size_t base = (size_t)blockIdx.x * CE;
    int e = threadIdx.x * 2;
    ushort2 s = *(const ushort2*)&src[base + e];
    ushort2 a = *(const ushort2*)&ao[base + e];
    float x0 = bf2f(s.x) + bf2f(a.x), x1 = bf2f(s.y) + bf2f(a.y);
    float mu = blockSum256(x0 + x1, sm) * (1.f / CE);
    float d0 = x0 - mu, d1 = x1 - mu;
    float var = blockSum256(d0 * d0 + d1 * d1, sm) * (1.f / CE);
    float rs = rsqrtf(var + EPS);
    ushort2 w;
    w.x = f2bf(d0 * rs * g[e] + be[e]);
    w.y = f2bf(d1 * rs * g[e + 1] + be[e + 1]);
    *(ushort2*)&o[base + e] = w;
}

__global__ __launch_bounds__(256) void ln2_kernel(
    const bf16_t* __restrict__ a, const bf16_t* __restrict__ b,
    const float* __restrict__ g, const float* __restrict__ be,
    float* __restrict__ o) {
    __shared__ float sm[4];
    size_t base = (size_t)blockIdx.x * CE;
    int e = threadIdx.x * 2;
    ushort2 aa = *(const ushort2*)&a[base + e];
    ushort2 bb = *(const ushort2*)&b[base + e];
    float x0 = bf2f(aa.x) + bf2f(bb.x), x1 = bf2f(aa.y) + bf2f(bb.y);
    float mu = blockSum256(x0 + x1, sm) * (1.f / CE);
    float d0 = x0 - mu, d1 = x1 - mu;
    float var = blockSum256(d0 * d0 + d1 * d1, sm) * (1.f / CE);
    float rs = rsqrtf(var + EPS);
    float2 w;
    w.x = d0 * rs * g[e] + be[e];
    w.y = d1 * rs * g[e + 1] + be[e + 1];
    *(float2*)&o[base + e] = w;
}

// ---------------- host ----------------
extern "C" void kernel_launch(void* const* d_in, const int* in_sizes, int n_in,
                              void* d_out, int out_size, void* d_ws, size_t ws_size,
                              hipStream_t stream) {
    const float* src  = (const float*)d_in[0];
    const float* mask = (const float*)d_in[1];
    const float* W1   = (const float*)d_in[2];
    const float* b1   = (const float*)d_in[3];
    const float* W2   = (const float*)d_in[4];
    const float* b2   = (const float*)d_in[5];
    const float* g1   = (const float*)d_in[6];
    const float* be1  = (const float*)d_in[7];
    const float* g2   = (const float*)d_in[8];
    const float* be2  = (const float*)d_in[9];
    float* out = (float*)d_out;
    char* ws = (char*)d_ws;

    hipFuncSetAttribute(reinterpret_cast<const void*>(&gemm256<3>), hipFuncAttributeMaxDynamicSharedMemorySize, 131072);
    hipFuncSetAttribute(reinterpret_cast<const void*>(&gemm256<4>), hipFuncAttributeMaxDynamicSharedMemorySize, 131072);
    hipFuncSetAttribute(reinterpret_cast<const void*>(&gemm256s<1>), hipFuncAttributeMaxDynamicSharedMemorySize, 131072);
    hipFuncSetAttribute(reinterpret_cast<const void*>(&gemm256_sym), hipFuncAttributeMaxDynamicSharedMemorySize, 131072);

    // ---- workspace layout (MiB offsets) ----
    // [0,256)   scores/probs bf16 (all 32)  | FFN: [0,64)=src2, [64,128)=ff, [128,384)=H
    // [256,320) src_bf
    // [320,384) srcT
    // [384,448) attnO (bf16)
    // [448,452) W1T, W2T
    const size_t MB = 1024 * 1024;
    bf16_t* probs  = (bf16_t*)(ws);              // scores in-place -> probs
    bf16_t* src_bf = (bf16_t*)(ws + 256 * MB);
    bf16_t* srcT   = (bf16_t*)(ws + 320 * MB);
    bf16_t* attnO  = (bf16_t*)(ws + 384 * MB);
    bf16_t* W1T    = (bf16_t*)(ws + 448 * MB);
    bf16_t* W2T    = (bf16_t*)(ws + 450 * MB);
    bf16_t* src2   = (bf16_t*)(ws);              // overlays probs (dead after PV)
    bf16_t* ff     = (bf16_t*)(ws + 64 * MB);    // overlays probs
    bf16_t* H      = (bf16_t*)(ws + 128 * MB);   // overlays probs tail
    if (ws_size < 452 * MB) return;

    // ---- conversions (src conv + transpose fused; weights separate) ----
    cvt_transpose<<<dim3(CE / 32, CN / 32, 32), 256, 0, stream>>>(src, src_bf, srcT);
    transpose_f32_bf16<<<dim3(CF / 32, CE / 32, 1), 256, 0, stream>>>(W1, W1T, CE, CF);
    transpose_f32_bf16<<<dim3(CE / 32, CF / 32, 1), 256, 0, stream>>>(W2, W2T, CF, CE);

    // ---- attention: ONE sym-scores dispatch (all 32), then per-group
    //      softmax -> PV (probs group stays L3-warm between the two) ----
    gemm256_sym<<<dim3(36, 1, 32), 512, 131072, stream>>>(
        src_bf, probs, SCALE, CN, CE,
        (long long)CN * CE, (long long)CN * CN);
    for (int g0 = 0; g0 < CB * CC; g0 += GRP) {
        bf16_t* probs_g = probs + (size_t)g0 * CN * CN;
        softmax_bf16<<<dim3(GRP * CN), 256, 0, stream>>>(probs_g, mask, g0);
        gemm256<3><<<dim3(CE / 256, CN / 256, GRP), 512, 131072, stream>>>(
            probs_g, srcT + (size_t)g0 * CE * CN, attnO + (size_t)g0 * CN * CE,
            nullptr, 1.0f, CE, CN,
            (long long)CN * CN, (long long)CE * CN, (long long)CN * CE);
    }
    ln1_kernel<<<dim3(CB * CC * CN), 256, 0, stream>>>(src_bf, attnO, g1, be1, src2);

    // ---- FFN + final LN (single chunk) ----
    gemm256s<1><<<dim3(CF / 256, MCH / 256, 1), 512, 131072, stream>>>(
        src2, W1T, H, b1, 1.0f, CF, CE, 0, 0, 0);
    gemm256<4><<<dim3(CE / 256, MCH / 256, 1), 512, 131072, stream>>>(
        H, W2T, ff, b2, 1.0f, CE, CF, 0, 0, 0);
    ln2_kernel<<<dim3(MCH), 256, 0, stream>>>(src2, ff, g2, be2, out);
}